// Round 12
// baseline (102.295 us; speedup 1.0000x reference)
//
#include <hip/hip_runtime.h>
#include <math.h>
#include <stdint.h>

#define TT 2048
#define BB 2
#define DD 768
#define HH 12
#define DHH 64
#define DTT 32
#define NROW 4096  // B*T

typedef float v4 __attribute__((ext_vector_type(4)));
typedef __attribute__((ext_vector_type(8))) short s8v;      // 8 bf16 (4 VGPRs)
typedef __attribute__((ext_vector_type(4))) float f4v;      // MFMA acc
typedef unsigned short u16;
typedef __attribute__((ext_vector_type(4))) unsigned short us4;

__device__ __forceinline__ u16 f2bf(float x) {
  unsigned u = __builtin_bit_cast(unsigned, x);
  u += 0x7fffu + ((u >> 16) & 1u);
  return (u16)(u >> 16);
}
__device__ __forceinline__ float bf2f(u16 b) {
  return __builtin_bit_cast(float, (unsigned)b << 16);
}
__device__ __forceinline__ float wave_sum(float v) {
#pragma unroll
  for (int m = 32; m > 0; m >>= 1) v += __shfl_xor(v, m, 64);
  return v;
}
__device__ __forceinline__ void gload16(const void* g, void* l) {
  __builtin_amdgcn_global_load_lds(
      (const __attribute__((address_space(1))) unsigned int*)g,
      (__attribute__((address_space(3))) unsigned int*)l, 16, 0, 0);
}
// counted waits + raw barrier (no vmcnt(0) drain mid-loop)
__device__ __forceinline__ void wait_vm5() {
  asm volatile("s_waitcnt vmcnt(5)" ::: "memory");
  __builtin_amdgcn_sched_barrier(0);
}
__device__ __forceinline__ void wait_vm2() {
  asm volatile("s_waitcnt vmcnt(2)" ::: "memory");
  __builtin_amdgcn_sched_barrier(0);
}
__device__ __forceinline__ void wait_vm0() {
  asm volatile("s_waitcnt vmcnt(0)" ::: "memory");
  __builtin_amdgcn_sched_barrier(0);
}
__device__ __forceinline__ void raw_barrier() {
  asm volatile("s_barrier" ::: "memory");
}
// 16B-chunk swizzle within a row's 64B k-tile group: chunk ^= (row>>1)&3.
// Stored pre-swizzled in global; ds_read applies the same XOR (involution).
__device__ __forceinline__ int swz_col(int row, int col) {
  int ch = (col >> 3) & 3;
  return (col & ~24) | (((ch ^ ((row >> 1) & 3)) & 3) << 3);
}

// ------ prep: time tables (recurrence) + swizzled f32->bf16 conversions -----
__global__ __launch_bounds__(256) void prep(
    const float* __restrict__ tang, const float* __restrict__ hdelta,
    const float* __restrict__ s, const float* __restrict__ wq,
    const float* __restrict__ wk, const float* __restrict__ wv,
    const float* __restrict__ wo, u16* __restrict__ timeqb,
    u16* __restrict__ timekb, u16* __restrict__ sb, u16* __restrict__ wqb,
    u16* __restrict__ wkvb, u16* __restrict__ wob) {
  int bid = blockIdx.x;
  if (bid < 192) {
    // one thread per (h,d,16-t chunk); 3 sincosf + 15 rotations
    int idx = bid * 256 + threadIdx.x;  // 49152
    int d = idx & 31;
    int h = (idx >> 5) % HH;
    int tc = idx / (32 * HH);           // 0..127
    int t0 = tc * 16;
    float ang = tang[h * DTT + d];
    float ca, sa;
    sincosf(ang, &sa, &ca);
    float ck, sk, cq, sq;
    sincosf((float)t0 * ang, &sk, &ck);
    sincosf(((float)t0 + hdelta[h]) * ang, &sq, &cq);
#pragma unroll
    for (int j = 0; j < 16; ++j) {
      int t = t0 + j;
      timekb[t * DD + h * DHH + d]       = f2bf((ck + sk) * 0.125f);
      timekb[t * DD + h * DHH + d + DTT] = f2bf((ck - sk) * 0.125f);
      timeqb[t * DD + h * DHH + d]       = f2bf((cq + sq) * 0.125f);
      timeqb[t * DD + h * DHH + d + DTT] = f2bf((cq - sq) * 0.125f);
      float ck2 = ck * ca - sk * sa;
      sk = sk * ca + ck * sa;
      ck = ck2;
      float cq2 = cq * ca - sq * sa;
      sq = sq * ca + cq * sa;
      cq = cq2;
    }
    return;
  }
  int idx = (bid - 192) * 256 + threadIdx.x;
  int off = idx * 4;
  const float* src;
  u16* dst;
  int so, rr, cc;
  if (off < 3145728) {                      // states -> Abf (swizzled)
    src = s; dst = sb; so = off; rr = so / 768; cc = so % 768;
  } else if (off < 3735552) {               // Wq (swizzled)
    src = wq; dst = wqb; so = off - 3145728; rr = so / 768; cc = so % 768;
  } else if (off < 4325376) {               // Wk -> head-major + swizzle
    src = wk; so = off - 3735552;
    int j = so / 768; cc = so - j * 768;
    int h = j >> 6, r = j & 63;
    dst = wkvb; rr = h * 128 + r;
  } else if (off < 4915200) {               // Wv -> head-major + swizzle
    src = wv; so = off - 4325376;
    int j = so / 768; cc = so - j * 768;
    int h = j >> 6, r = j & 63;
    dst = wkvb; rr = h * 128 + 64 + r;
  } else {                                  // Wo (swizzled)
    src = wo; dst = wob; so = off - 4915200; rr = so / 768; cc = so % 768;
  }
  int dof = rr * 768 + swz_col(rr, cc);
  v4 f = *(const v4*)&src[so];
  us4 o;
#pragma unroll
  for (int j = 0; j < 4; ++j) o[j] = f2bf(f[j]);
  *(us4*)&dst[dof] = o;
}

// ---- gemm_qkv_fused: 64x256 tiles, 576 blocks (4/CU, all co-resident).
// 2-buf double-barrier counted-vmcnt pipe; 16 MFMA per 8 ds_read per wave/step.
// bx<3: Q (4 heads/block, one per wave) -> qsum epilogue.
// bx in [3,9): heads 2(bx-3),2(bx-3)+1; waves 0/2 = K -> softmax -> P(LDS);
//              waves 1/3 = V -> P*V -> bf16 kv.
__global__ __launch_bounds__(256) void gemm_qkv_fused(
    const u16* __restrict__ A, const u16* __restrict__ Wqb,
    const u16* __restrict__ Wkvb, const float* __restrict__ qb,
    const float* __restrict__ bk, const float* __restrict__ bv,
    const int* __restrict__ amask, float* __restrict__ qsum,
    u16* __restrict__ kvb) {
  __shared__ __align__(16) u16 As[2][2048];  // A 64x32/buf
  __shared__ __align__(16) u16 Bs[2][8192];  // B 256x32/buf; epilogue P overlay
  const int tid = threadIdx.x;
  const int l = tid & 63;
  const int w = tid >> 6;
  const int bx = blockIdx.x;
  const bool isQ = bx < 3;
  const int i0 = blockIdx.y * 64;
  const u16* Bbase = isQ ? (Wqb + (size_t)bx * 256 * 768)
                         : (Wkvb + (size_t)(bx - 3) * 256 * 768);
  const int srow = tid >> 2, scol = (tid & 3) * 8;
  const u16* gA0 = A + (size_t)(i0 + srow) * 768 + scol;   // 64 rows
  const u16* gB0 = Bbase + (size_t)srow * 768 + scol;      // +64*768 per chunk
  const int lo = tid * 8;
  f4v acc[4][4];
#pragma unroll
  for (int m = 0; m < 4; ++m)
#pragma unroll
    for (int n = 0; n < 4; ++n) acc[m][n] = (f4v){0.f, 0.f, 0.f, 0.f};

#define STAGE(kt, b)                                          \
  do {                                                        \
    int kb_ = (kt) << 5;                                      \
    gload16(gA0 + kb_, &As[b][lo]);                           \
    gload16(gB0 + kb_, &Bs[b][lo]);                           \
    gload16(gB0 + kb_ + 64 * 768, &Bs[b][2048 + lo]);         \
    gload16(gB0 + kb_ + 128 * 768, &Bs[b][4096 + lo]);        \
    gload16(gB0 + kb_ + 192 * 768, &Bs[b][6144 + lo]);        \
  } while (0)

  STAGE(0, 0);
  STAGE(1, 1);
  // swizzled, loop-invariant frag addresses
  int aoff[4], boff[4];
#pragma unroll
  for (int m = 0; m < 4; ++m) {
    int row = (l & 15) + m * 16;
    aoff[m] = row * 32 + (((l >> 4) ^ ((row >> 1) & 3)) << 3);
  }
#pragma unroll
  for (int n = 0; n < 4; ++n) {
    int row = w * 64 + (l & 15) + n * 16;
    boff[n] = row * 32 + (((l >> 4) ^ ((row >> 1) & 3)) << 3);
  }
  int cb = 0;
  for (int kt = 0; kt < 24; ++kt) {
    if (kt < 23) wait_vm5();          // tile kt's own 5 loads done
    else wait_vm0();
    raw_barrier();                    // all waves' tile-kt portions landed
    s8v af[4], bf4[4];
#pragma unroll
    for (int m = 0; m < 4; ++m) af[m] = *(const s8v*)&As[cb][aoff[m]];
#pragma unroll
    for (int n = 0; n < 4; ++n) bf4[n] = *(const s8v*)&Bs[cb][boff[n]];
#pragma unroll
    for (int m = 0; m < 4; ++m)
#pragma unroll
      for (int n = 0; n < 4; ++n)
        acc[m][n] =
            __builtin_amdgcn_mfma_f32_16x16x32_bf16(af[m], bf4[n], acc[m][n], 0, 0, 0);
    raw_barrier();                    // all waves consumed buf cb
    if (kt + 2 < 24) STAGE(kt + 2, cb);  // restage just-read buf
    cb ^= 1;
  }
  __syncthreads();  // drain before LDS reuse in epilogue

  // output rows: row = i0 + (l>>4)*4 + m*16 + r  (all 64 rows per wave)
  const int crow = i0 + (l >> 4) * 4;
  if (isQ) {
    const int head = bx * 4 + w;      // wave owns one head's 64 cols
    float eqb[4];
#pragma unroll
    for (int n = 0; n < 4; ++n)
      eqb[n] = expf(qb[head * 64 + n * 16 + (l & 15)]);
#pragma unroll
    for (int m = 0; m < 4; ++m)
#pragma unroll
      for (int r = 0; r < 4; ++r) {
        float ssum = 0.f;
#pragma unroll
        for (int n = 0; n < 4; ++n)
          ssum += 1.f / (1.f + expf(-(acc[m][n][r] - eqb[n])));
#pragma unroll
        for (int mm = 8; mm > 0; mm >>= 1) ssum += __shfl_xor(ssum, mm, 64);
        int row = crow + m * 16 + r;
        if ((l & 15) == 0)
          qsum[row * HH + head] = ssum * (float)amask[row] * (1.f / 64.f);
      }
  } else {
    const int hloc = w >> 1;                 // 0 or 1
    const int head = (bx - 3) * 2 + hloc;
    u16* Ps = &Bs[0][0] + hloc * 4352;       // 64 rows x stride 68
    if ((w & 1) == 0) {  // K wave -> row softmax -> P to LDS
#pragma unroll
      for (int m = 0; m < 4; ++m)
#pragma unroll
        for (int r = 0; r < 4; ++r) {
          int row = crow + m * 16 + r;
          float mk = (float)amask[row];
          float kv4[4];
#pragma unroll
          for (int n = 0; n < 4; ++n)
            kv4[n] = (acc[m][n][r] + bk[head * 64 + n * 16 + (l & 15)]) * mk;
          float mx = fmaxf(fmaxf(kv4[0], kv4[1]), fmaxf(kv4[2], kv4[3]));
#pragma unroll
          for (int mm = 8; mm > 0; mm >>= 1)
            mx = fmaxf(mx, __shfl_xor(mx, mm, 64));
          float e[4], es = 0.f;
#pragma unroll
          for (int n = 0; n < 4; ++n) { e[n] = expf(kv4[n] - mx); es += e[n]; }
#pragma unroll
          for (int mm = 8; mm > 0; mm >>= 1) es += __shfl_xor(es, mm, 64);
          float inv = 1.f / es;
          int lrow = (l >> 4) * 4 + m * 16 + r;
#pragma unroll
          for (int n = 0; n < 4; ++n)
            Ps[lrow * 68 + n * 16 + (l & 15)] = f2bf(e[n] * inv);
        }
    }
    __syncthreads();  // block-uniform branch: all waves of KV blocks reach
    if ((w & 1) == 1) {  // V wave: kv = P * V -> bf16
#pragma unroll
      for (int m = 0; m < 4; ++m)
#pragma unroll
        for (int r = 0; r < 4; ++r) {
          int row = crow + m * 16 + r;
          int lrow = (l >> 4) * 4 + m * 16 + r;
#pragma unroll
          for (int n = 0; n < 4; ++n) {
            int d = n * 16 + (l & 15);
            float p = bf2f(Ps[lrow * 68 + d]);
            float vv = acc[m][n][r] + bv[head * 64 + d];
            kvb[((size_t)row * HH + head) * 64 + d] = f2bf(p * vv);
          }
        }
    }
  }
}

// --- Mpart[blk][d][r] over 64-t slices (32 splits, 768 blocks, bf16 in) ------
__global__ __launch_bounds__(256) void calc_M(
    const u16* __restrict__ timekb, const u16* __restrict__ kvb,
    float* __restrict__ Mpart) {
  int blk = blockIdx.x;  // bh*32 + split
  int split = blk & 31;
  int bh = blk >> 5;
  int b = bh / HH, h = bh % HH;
  __shared__ float Tk[64][68];
  __shared__ float Kv[64][68];
  int tid = threadIdx.x;
  int tx = tid & 15, ty = tid >> 4;
  float acc[4][4] = {};
  int t0 = split * 64;
#pragma unroll
  for (int p = 0; p < 4; ++p) {
    int f = tid + 256 * p;
    int r = f >> 4, c4 = (f & 15) << 2;
    int t = t0 + r;
    us4 tk = *(const us4*)&timekb[(size_t)t * DD + h * DHH + c4];
    us4 kv = *(const us4*)&kvb[((size_t)(b * TT + t) * HH + h) * 64 + c4];
#pragma unroll
    for (int j = 0; j < 4; ++j) {
      Tk[r][c4 + j] = bf2f(tk[j]);
      Kv[r][c4 + j] = bf2f(kv[j]);
    }
  }
  __syncthreads();
#pragma unroll
  for (int kk = 0; kk < 64; ++kk) {
    v4 a = *(const v4*)&Tk[kk][ty * 4];
    v4 bv4 = *(const v4*)&Kv[kk][tx * 4];
#pragma unroll
    for (int r = 0; r < 4; ++r)
#pragma unroll
      for (int c = 0; c < 4; ++c) acc[r][c] += a[r] * bv4[c];
  }
#pragma unroll
  for (int r = 0; r < 4; ++r)
#pragma unroll
    for (int c = 0; c < 4; ++c)
      Mpart[(size_t)blk * 4096 + (tx * 4 + c) * 64 + (ty * 4 + r)] = acc[r][c];
}

// ------- Mtb[bh][p] = sum_{s<32} Mpart[bh*32+s][p] -> bf16 (fixed order) ------
__global__ __launch_bounds__(256) void reduce_M(
    const float* __restrict__ Mpart, u16* __restrict__ Mtb) {
  int idx = blockIdx.x * 256 + threadIdx.x;
  int bh = idx >> 12;
  int p = idx & 4095;
  float s = 0.f;
#pragma unroll
  for (int sp = 0; sp < 32; ++sp)
    s += Mpart[(size_t)((bh << 5) + sp) * 4096 + p];
  Mtb[(size_t)bh * 4096 + p] = f2bf(s);
}

// ------ loading = qsum * (timeq @ M) via MFMA -> bf16 (PRE-SWIZZLED store) ----
// grid (32, 24): 64-t chunks, each wave 16 rows x 64 cols.
__global__ __launch_bounds__(256) void calc_loading_mfma(
    const u16* __restrict__ timeqb, const u16* __restrict__ Mtb,
    const float* __restrict__ qsum, u16* __restrict__ loading) {
  const int bh = blockIdx.y;
  const int b = bh / HH, h = bh % HH;
  const int t0 = blockIdx.x * 64;
  __shared__ __align__(16) u16 Ms[64 * 72];
  for (int p = threadIdx.x; p < 4096; p += 256)
    Ms[(p >> 6) * 72 + (p & 63)] = Mtb[(size_t)bh * 4096 + p];
  __syncthreads();
  const int l = threadIdx.x & 63, w = threadIdx.x >> 6;
  f4v acc[4];
#pragma unroll
  for (int n = 0; n < 4; ++n) acc[n] = (f4v){0.f, 0.f, 0.f, 0.f};
  const int arow = t0 + w * 16 + (l & 15);
  const int dcol = l & 15;
#pragma unroll
  for (int ks = 0; ks < 2; ++ks) {
    const int k0 = ks * 32 + (l >> 4) * 8;
    s8v af, bf4[4];
    af = *(const s8v*)&timeqb[(size_t)arow * DD + h * DHH + k0];
#pragma unroll
    for (int n = 0; n < 4; ++n)
      bf4[n] = *(const s8v*)&Ms[(dcol + n * 16) * 72 + k0];
#pragma unroll
    for (int n = 0; n < 4; ++n)
      acc[n] = __builtin_amdgcn_mfma_f32_16x16x32_bf16(af, bf4[n], acc[n], 0, 0, 0);
  }
  const int trow = t0 + w * 16 + (l >> 4) * 4;
  float qs[4];
#pragma unroll
  for (int r = 0; r < 4; ++r)
    qs[r] = qsum[(b * TT + trow + r) * HH + h];
#pragma unroll
  for (int n = 0; n < 4; ++n)
#pragma unroll
    for (int r = 0; r < 4; ++r) {
      int i = b * TT + trow + r;
      int col = h * DHH + n * 16 + (l & 15);
      loading[(size_t)i * DD + swz_col(i, col)] = f2bf(qs[r] * acc[n][r]);
    }
}

// ------ gemm_out: 64x64 tiles, 768 blocks (3/CU); 3-buf single-barrier ------
__global__ __launch_bounds__(256) void gemm_out(
    const u16* __restrict__ A, const u16* __restrict__ B, float* __restrict__ C,
    const float* __restrict__ bias, const float* __restrict__ res) {
  __shared__ __align__(16) u16 As[3][2048];
  __shared__ __align__(16) u16 Bs[3][2048];
  const int tid = threadIdx.x;
  const int l = tid & 63;
  const int w = tid >> 6;
  const int wr = w >> 1, wc = w & 1;
  const int i0 = blockIdx.y * 64, j0 = blockIdx.x * 64;
  const int srow = tid >> 2, scol = (tid & 3) * 8;
  const u16* gA0 = A + (size_t)(i0 + srow) * 768 + scol;
  const u16* gB0 = B + (size_t)(j0 + srow) * 768 + scol;
  const int lo = tid * 8;
  f4v acc[2][2];
#pragma unroll
  for (int m = 0; m < 2; ++m)
#pragma unroll
    for (int n = 0; n < 2; ++n) acc[m][n] = (f4v){0.f, 0.f, 0.f, 0.f};

#define STAGE2(kt, b)                 \
  do {                                \
    int kb_ = (kt) << 5;              \
    gload16(gA0 + kb_, &As[b][lo]);   \
    gload16(gB0 + kb_, &Bs[b][lo]);   \
  } while (0)

  STAGE2(0, 0);
  STAGE2(1, 1);
  int aoff[2], boff[2];
#pragma unroll
  for (int m = 0; m < 2; ++m) {
    int row = wr * 32 + (l & 15) + m * 16;
    aoff[m] = row * 32 + (((l >> 4) ^ ((row >> 1) & 3)) << 3);
  }
#pragma unroll
  for (int n = 0; n < 2; ++n) {
    int row = wc * 32 + (l & 15) + n * 16;
    boff[n] = row * 32 + (((l >> 4) ^ ((row >> 1) & 3)) << 3);
  }
  int cb = 0;
  for (int kt = 0; kt < 24; ++kt) {
    if (kt < 23) wait_vm2();
    else wait_vm0();
    raw_barrier();
    if (kt + 2 < 24) STAGE2(kt + 2, (cb + 2) % 3);
    s8v af[2], bf4[2];
#pragma unroll
    for (int m = 0; m < 2; ++m) af[m] = *(const s8v*)&As[cb][aoff[m]];
#pragma unroll
    for (int n = 0; n < 2; ++n) bf4[n] = *(const s8v*)&Bs[cb][boff[n]];
#pragma unroll
    for (int m = 0; m < 2; ++m)
#pragma unroll
      for (int n = 0; n < 2; ++n)
        acc[m][n] =
            __builtin_amdgcn_mfma_f32_16x16x32_bf16(af[m], bf4[n], acc[m][n], 0, 0, 0);
    cb = (cb == 2) ? 0 : cb + 1;
  }
  const int crow = i0 + wr * 32 + (l >> 4) * 4;
  const int ccol = j0 + wc * 32 + (l & 15);
#pragma unroll
  for (int m = 0; m < 2; ++m)
#pragma unroll
    for (int n = 0; n < 2; ++n) {
      int col = ccol + n * 16;
      size_t base = (size_t)(crow + m * 16) * 768 + col;
#pragma unroll
      for (int r = 0; r < 4; ++r)
        C[base + (size_t)r * 768] =
            acc[m][n][r] + bias[col] + res[base + (size_t)r * 768];
    }
}

// ---------------- LayerNorm ----------------
__global__ __launch_bounds__(256) void layernorm(
    const float* __restrict__ X, const float* __restrict__ gamma,
    const float* __restrict__ beta, float* __restrict__ out) {
  int i = blockIdx.x;
  const float* x = X + (size_t)i * 768;
  float vals[3];
  float s = 0.f, s2 = 0.f;
#pragma unroll
  for (int p = 0; p < 3; ++p) {
    float v = x[threadIdx.x + 256 * p];
    vals[p] = v;
    s += v;
    s2 += v * v;
  }
  s = wave_sum(s);
  s2 = wave_sum(s2);
  __shared__ float red[8];
  int w = threadIdx.x >> 6;
  if ((threadIdx.x & 63) == 0) {
    red[w] = s;
    red[4 + w] = s2;
  }
  __syncthreads();
  float stot = red[0] + red[1] + red[2] + red[3];
  float s2tot = red[4] + red[5] + red[6] + red[7];
  float mu = stot * (1.f / 768.f);
  float var = s2tot * (1.f / 768.f) - mu * mu;
  float rs = rsqrtf(var + 1e-5f);
#pragma unroll
  for (int p = 0; p < 3; ++p) {
    int j = threadIdx.x + 256 * p;
    out[(size_t)i * 768 + j] = (vals[p] - mu) * rs * gamma[j] + beta[j];
  }
}

extern "C" void kernel_launch(void* const* d_in, const int* in_sizes, int n_in,
                              void* d_out, int out_size, void* d_ws,
                              size_t ws_size, hipStream_t stream) {
  const float* states = (const float*)d_in[0];
  const int* amask    = (const int*)d_in[1];
  const float* Wq     = (const float*)d_in[2];
  const float* Wk     = (const float*)d_in[3];
  const float* bk     = (const float*)d_in[4];
  const float* Wv     = (const float*)d_in[5];
  const float* bv     = (const float*)d_in[6];
  const float* Wo     = (const float*)d_in[7];
  const float* bo     = (const float*)d_in[8];
  const float* qb     = (const float*)d_in[9];
  const float* tang   = (const float*)d_in[10];
  const float* hdelta = (const float*)d_in[11];
  const float* gamma  = (const float*)d_in[12];
  const float* beta   = (const float*)d_in[13];
  float* out = (float*)d_out;
  float* ws = (float*)d_ws;

  // workspace (float-unit offsets; ~49 MB total)
  u16* timeqb = (u16*)(ws + 0);          // 786432 f
  u16* timekb = (u16*)(ws + 786432);     // 786432 f
  u16* Abf    = (u16*)(ws + 1572864);    // 1572864 f
  u16* Wqb    = (u16*)(ws + 3145728);    // 294912 f
  u16* Wkvb   = (u16*)(ws + 3440640);    // 589824 f
  u16* Wob    = (u16*)(ws + 4030464);    // 294912 f
  float* qsum = ws + 4325376;            // 49152 f
  u16* kvb    = (u16*)(ws + 4374528);    // 786432 f
  float* Mpart= ws + 5160960;            // 3145728 f (32 splits)
  u16* Mtb    = (u16*)(ws + 8306688);    // 24576 f
  u16* loadb  = (u16*)(ws + 8331264);    // 786432 f
  float* xbuf = ws + 9117696;            // 3145728 f

  prep<<<5568, 256, 0, stream>>>(tang, hdelta, states, Wq, Wk, Wv, Wo, timeqb,
                                 timekb, Abf, Wqb, Wkvb, Wob);
  gemm_qkv_fused<<<dim3(9, 64), 256, 0, stream>>>(Abf, Wqb, Wkvb, qb, bk, bv,
                                                  amask, qsum, kvb);
  calc_M<<<768, 256, 0, stream>>>(timekb, kvb, Mpart);
  reduce_M<<<384, 256, 0, stream>>>(Mpart, Mtb);
  calc_loading_mfma<<<dim3(32, 24), 256, 0, stream>>>(timeqb, Mtb, qsum, loadb);
  gemm_out<<<dim3(12, 64), 256, 0, stream>>>(loadb, Wob, xbuf, bo, states);
  layernorm<<<4096, 256, 0, stream>>>(xbuf, gamma, beta, out);
}

// Round 14
// 91.475 us; speedup vs baseline: 1.1183x; 1.1183x over previous
//
#include <hip/hip_runtime.h>
#include <math.h>
#include <stdint.h>

#define TT 2048
#define BB 2
#define DD 768
#define HH 12
#define DHH 64
#define DTT 32
#define NROW 4096  // B*T

typedef float v4 __attribute__((ext_vector_type(4)));
typedef __attribute__((ext_vector_type(8))) short s8v;      // 8 bf16 (4 VGPRs)
typedef __attribute__((ext_vector_type(4))) float f4v;      // MFMA acc
typedef unsigned short u16;
typedef __attribute__((ext_vector_type(4))) unsigned short us4;

__device__ __forceinline__ u16 f2bf(float x) {
  unsigned u = __builtin_bit_cast(unsigned, x);
  u += 0x7fffu + ((u >> 16) & 1u);
  return (u16)(u >> 16);
}
__device__ __forceinline__ float bf2f(u16 b) {
  return __builtin_bit_cast(float, (unsigned)b << 16);
}
__device__ __forceinline__ float wave_sum(float v) {
#pragma unroll
  for (int m = 32; m > 0; m >>= 1) v += __shfl_xor(v, m, 64);
  return v;
}
__device__ __forceinline__ void gload16(const void* g, void* l) {
  __builtin_amdgcn_global_load_lds(
      (const __attribute__((address_space(1))) unsigned int*)g,
      (__attribute__((address_space(3))) unsigned int*)l, 16, 0, 0);
}
// counted waits + raw barrier (no vmcnt(0) drain mid-loop)
__device__ __forceinline__ void wait_vm3() {
  asm volatile("s_waitcnt vmcnt(3)" ::: "memory");
  __builtin_amdgcn_sched_barrier(0);
}
__device__ __forceinline__ void wait_vm2() {
  asm volatile("s_waitcnt vmcnt(2)" ::: "memory");
  __builtin_amdgcn_sched_barrier(0);
}
__device__ __forceinline__ void wait_vm0() {
  asm volatile("s_waitcnt vmcnt(0)" ::: "memory");
  __builtin_amdgcn_sched_barrier(0);
}
__device__ __forceinline__ void raw_barrier() {
  asm volatile("s_barrier" ::: "memory");
}
// 16B-chunk swizzle within a row's 64B k-tile group: chunk ^= (row>>1)&3.
// Stored pre-swizzled in global; ds_read applies the same XOR (involution).
__device__ __forceinline__ int swz_col(int row, int col) {
  int ch = (col >> 3) & 3;
  return (col & ~24) | (((ch ^ ((row >> 1) & 3)) & 3) << 3);
}

// ------ prep: time tables (recurrence) + swizzled f32->bf16 conversions -----
__global__ __launch_bounds__(256) void prep(
    const float* __restrict__ tang, const float* __restrict__ hdelta,
    const float* __restrict__ s, const float* __restrict__ wq,
    const float* __restrict__ wk, const float* __restrict__ wv,
    const float* __restrict__ wo, u16* __restrict__ timeqb,
    u16* __restrict__ timekb, u16* __restrict__ sb, u16* __restrict__ wqb,
    u16* __restrict__ wkvb, u16* __restrict__ wob) {
  int bid = blockIdx.x;
  if (bid < 192) {
    // one thread per (h,d,16-t chunk); 3 sincosf + 15 rotations
    int idx = bid * 256 + threadIdx.x;  // 49152
    int d = idx & 31;
    int h = (idx >> 5) % HH;
    int tc = idx / (32 * HH);           // 0..127
    int t0 = tc * 16;
    float ang = tang[h * DTT + d];
    float ca, sa;
    sincosf(ang, &sa, &ca);
    float ck, sk, cq, sq;
    sincosf((float)t0 * ang, &sk, &ck);
    sincosf(((float)t0 + hdelta[h]) * ang, &sq, &cq);
#pragma unroll
    for (int j = 0; j < 16; ++j) {
      int t = t0 + j;
      timekb[t * DD + h * DHH + d]       = f2bf((ck + sk) * 0.125f);
      timekb[t * DD + h * DHH + d + DTT] = f2bf((ck - sk) * 0.125f);
      timeqb[t * DD + h * DHH + d]       = f2bf((cq + sq) * 0.125f);
      timeqb[t * DD + h * DHH + d + DTT] = f2bf((cq - sq) * 0.125f);
      float ck2 = ck * ca - sk * sa;
      sk = sk * ca + ck * sa;
      ck = ck2;
      float cq2 = cq * ca - sq * sa;
      sq = sq * ca + cq * sa;
      cq = cq2;
    }
    return;
  }
  int idx = (bid - 192) * 256 + threadIdx.x;
  int off = idx * 4;
  const float* src;
  u16* dst;
  int so, rr, cc;
  if (off < 3145728) {                      // states -> Abf (swizzled)
    src = s; dst = sb; so = off; rr = so / 768; cc = so % 768;
  } else if (off < 3735552) {               // Wq (swizzled)
    src = wq; dst = wqb; so = off - 3145728; rr = so / 768; cc = so % 768;
  } else if (off < 4325376) {               // Wk -> head-major + swizzle
    src = wk; so = off - 3735552;
    int j = so / 768; cc = so - j * 768;
    int h = j >> 6, r = j & 63;
    dst = wkvb; rr = h * 128 + r;
  } else if (off < 4915200) {               // Wv -> head-major + swizzle
    src = wv; so = off - 4325376;
    int j = so / 768; cc = so - j * 768;
    int h = j >> 6, r = j & 63;
    dst = wkvb; rr = h * 128 + 64 + r;
  } else {                                  // Wo (swizzled)
    src = wo; dst = wob; so = off - 4915200; rr = so / 768; cc = so % 768;
  }
  int dof = rr * 768 + swz_col(rr, cc);
  v4 f = *(const v4*)&src[so];
  us4 o;
#pragma unroll
  for (int j = 0; j < 4; ++j) o[j] = f2bf(f[j]);
  *(us4*)&dst[dof] = o;
}

// ---- gemm_qkv_fused: 64x128 tiles, 1152 blocks; 2-buf double-barrier pipe
// (round-10 optimum: 25KB LDS -> 6 blocks/CU, all co-resident).
// bx<6: Q-region -> qsum epilogue. bx in [6,18): head = bx-6 -> softmax(K)*V.
__global__ __launch_bounds__(256) void gemm_qkv_fused(
    const u16* __restrict__ A, const u16* __restrict__ Wqb,
    const u16* __restrict__ Wkvb, const float* __restrict__ qb,
    const float* __restrict__ bk, const float* __restrict__ bv,
    const int* __restrict__ amask, float* __restrict__ qsum,
    u16* __restrict__ kvb) {
  __shared__ __align__(16) u16 As[2][2176];  // A 64x32/buf; both bufs = P 64x68
  __shared__ __align__(16) u16 Bs[2][4096];  // B 128x32/buf
  const int tid = threadIdx.x;
  const int l = tid & 63;
  const int w = tid >> 6;
  const int wr = w >> 1, wc = w & 1;
  const int bx = blockIdx.x;
  const bool isQ = bx < 6;
  const int i0 = blockIdx.y * 64;
  const u16* Bbase = isQ ? (Wqb + (size_t)bx * 128 * 768)
                         : (Wkvb + (size_t)(bx - 6) * 128 * 768);
  const int srow = tid >> 2, scol = (tid & 3) * 8;
  const u16* gA0 = A + (size_t)(i0 + srow) * 768 + scol;   // 64 rows
  const u16* gB0 = Bbase + (size_t)srow * 768 + scol;      // rows 0-63
  const u16* gB1 = gB0 + (size_t)64 * 768;                 // rows 64-127
  const int lo = tid * 8;
  f4v acc[2][4];
#pragma unroll
  for (int m = 0; m < 2; ++m)
#pragma unroll
    for (int n = 0; n < 4; ++n) acc[m][n] = (f4v){0.f, 0.f, 0.f, 0.f};

#define STAGE(kt, b)                       \
  do {                                     \
    int kb_ = (kt) << 5;                   \
    gload16(gA0 + kb_, &As[b][lo]);        \
    gload16(gB0 + kb_, &Bs[b][lo]);        \
    gload16(gB1 + kb_, &Bs[b][2048 + lo]); \
  } while (0)

  STAGE(0, 0);
  STAGE(1, 1);
  // swizzled, loop-invariant frag addresses
  int aoff[2], boff[4];
#pragma unroll
  for (int m = 0; m < 2; ++m) {
    int row = wr * 32 + (l & 15) + m * 16;
    aoff[m] = row * 32 + (((l >> 4) ^ ((row >> 1) & 3)) << 3);
  }
#pragma unroll
  for (int n = 0; n < 4; ++n) {
    int row = wc * 64 + (l & 15) + n * 16;
    boff[n] = row * 32 + (((l >> 4) ^ ((row >> 1) & 3)) << 3);
  }
  int cb = 0;
  for (int kt = 0; kt < 24; ++kt) {
    if (kt < 23) wait_vm3();          // tile kt's own 3 loads done
    else wait_vm0();
    raw_barrier();                    // all waves' tile-kt portions landed
    s8v af[2], bf4[4];
#pragma unroll
    for (int m = 0; m < 2; ++m) af[m] = *(const s8v*)&As[cb][aoff[m]];
#pragma unroll
    for (int n = 0; n < 4; ++n) bf4[n] = *(const s8v*)&Bs[cb][boff[n]];
#pragma unroll
    for (int m = 0; m < 2; ++m)
#pragma unroll
      for (int n = 0; n < 4; ++n)
        acc[m][n] =
            __builtin_amdgcn_mfma_f32_16x16x32_bf16(af[m], bf4[n], acc[m][n], 0, 0, 0);
    raw_barrier();                    // all waves consumed buf cb
    if (kt + 2 < 24) STAGE(kt + 2, cb);  // restage just-read buf
    cb ^= 1;
  }
  __syncthreads();  // drain before LDS reuse in epilogue

  const int crow = i0 + wr * 32 + (l >> 4) * 4;
  if (isQ) {
    const int head = bx * 2 + wc;
    float eqb[4];
#pragma unroll
    for (int n = 0; n < 4; ++n)
      eqb[n] = expf(qb[head * 64 + n * 16 + (l & 15)]);
#pragma unroll
    for (int m = 0; m < 2; ++m)
#pragma unroll
      for (int r = 0; r < 4; ++r) {
        float ssum = 0.f;
#pragma unroll
        for (int n = 0; n < 4; ++n)
          ssum += 1.f / (1.f + expf(-(acc[m][n][r] - eqb[n])));
#pragma unroll
        for (int mm = 8; mm > 0; mm >>= 1) ssum += __shfl_xor(ssum, mm, 64);
        int row = crow + m * 16 + r;
        if ((l & 15) == 0)
          qsum[row * HH + head] = ssum * (float)amask[row] * (1.f / 64.f);
      }
  } else {
    const int head = bx - 6;
    u16* Ps = &As[0][0];  // 64 rows x stride 68 = 4352 u16 (both A bufs)
    if (wc == 0) {        // K columns -> row softmax -> P to LDS
#pragma unroll
      for (int m = 0; m < 2; ++m)
#pragma unroll
        for (int r = 0; r < 4; ++r) {
          int row = crow + m * 16 + r;
          float mk = (float)amask[row];
          float kv4[4];
#pragma unroll
          for (int n = 0; n < 4; ++n)
            kv4[n] = (acc[m][n][r] + bk[head * 64 + n * 16 + (l & 15)]) * mk;
          float mx = fmaxf(fmaxf(kv4[0], kv4[1]), fmaxf(kv4[2], kv4[3]));
#pragma unroll
          for (int mm = 8; mm > 0; mm >>= 1)
            mx = fmaxf(mx, __shfl_xor(mx, mm, 64));
          float e[4], es = 0.f;
#pragma unroll
          for (int n = 0; n < 4; ++n) { e[n] = expf(kv4[n] - mx); es += e[n]; }
#pragma unroll
          for (int mm = 8; mm > 0; mm >>= 1) es += __shfl_xor(es, mm, 64);
          float inv = 1.f / es;
          int lrow = wr * 32 + (l >> 4) * 4 + m * 16 + r;
#pragma unroll
          for (int n = 0; n < 4; ++n)
            Ps[lrow * 68 + n * 16 + (l & 15)] = f2bf(e[n] * inv);
        }
    }
    __syncthreads();
    if (wc == 1) {  // V columns: kv = P * V -> bf16
#pragma unroll
      for (int m = 0; m < 2; ++m)
#pragma unroll
        for (int r = 0; r < 4; ++r) {
          int row = crow + m * 16 + r;
          int lrow = wr * 32 + (l >> 4) * 4 + m * 16 + r;
#pragma unroll
          for (int n = 0; n < 4; ++n) {
            int d = n * 16 + (l & 15);
            float p = bf2f(Ps[lrow * 68 + d]);
            float vv = acc[m][n][r] + bv[head * 64 + d];
            kvb[((size_t)row * HH + head) * 64 + d] = f2bf(p * vv);
          }
        }
    }
  }
}

// --- Mpart[blk][d][r] over 64-t slices (32 splits, 768 blocks, bf16 in) ------
__global__ __launch_bounds__(256) void calc_M(
    const u16* __restrict__ timekb, const u16* __restrict__ kvb,
    float* __restrict__ Mpart) {
  int blk = blockIdx.x;  // bh*32 + split
  int split = blk & 31;
  int bh = blk >> 5;
  int b = bh / HH, h = bh % HH;
  __shared__ float Tk[64][68];
  __shared__ float Kv[64][68];
  int tid = threadIdx.x;
  int tx = tid & 15, ty = tid >> 4;
  float acc[4][4] = {};
  int t0 = split * 64;
#pragma unroll
  for (int p = 0; p < 4; ++p) {
    int f = tid + 256 * p;
    int r = f >> 4, c4 = (f & 15) << 2;
    int t = t0 + r;
    us4 tk = *(const us4*)&timekb[(size_t)t * DD + h * DHH + c4];
    us4 kv = *(const us4*)&kvb[((size_t)(b * TT + t) * HH + h) * 64 + c4];
#pragma unroll
    for (int j = 0; j < 4; ++j) {
      Tk[r][c4 + j] = bf2f(tk[j]);
      Kv[r][c4 + j] = bf2f(kv[j]);
    }
  }
  __syncthreads();
#pragma unroll
  for (int kk = 0; kk < 64; ++kk) {
    v4 a = *(const v4*)&Tk[kk][ty * 4];
    v4 bv4 = *(const v4*)&Kv[kk][tx * 4];
#pragma unroll
    for (int r = 0; r < 4; ++r)
#pragma unroll
      for (int c = 0; c < 4; ++c) acc[r][c] += a[r] * bv4[c];
  }
#pragma unroll
  for (int r = 0; r < 4; ++r)
#pragma unroll
    for (int c = 0; c < 4; ++c)
      Mpart[(size_t)blk * 4096 + (tx * 4 + c) * 64 + (ty * 4 + r)] = acc[r][c];
}

// ------- Mtb[bh][p] = sum_{s<32} Mpart[bh*32+s][p] -> bf16 (fixed order) ------
__global__ __launch_bounds__(256) void reduce_M(
    const float* __restrict__ Mpart, u16* __restrict__ Mtb) {
  int idx = blockIdx.x * 256 + threadIdx.x;
  int bh = idx >> 12;
  int p = idx & 4095;
  float s = 0.f;
#pragma unroll
  for (int sp = 0; sp < 32; ++sp)
    s += Mpart[(size_t)((bh << 5) + sp) * 4096 + p];
  Mtb[(size_t)bh * 4096 + p] = f2bf(s);
}

// ------ loading = qsum * (timeq @ M) via MFMA -> bf16 (PRE-SWIZZLED store) ----
// grid (32, 24): 64-t chunks, each wave 16 rows x 64 cols.
__global__ __launch_bounds__(256) void calc_loading_mfma(
    const u16* __restrict__ timeqb, const u16* __restrict__ Mtb,
    const float* __restrict__ qsum, u16* __restrict__ loading) {
  const int bh = blockIdx.y;
  const int b = bh / HH, h = bh % HH;
  const int t0 = blockIdx.x * 64;
  __shared__ __align__(16) u16 Ms[64 * 72];
  for (int p = threadIdx.x; p < 4096; p += 256)
    Ms[(p >> 6) * 72 + (p & 63)] = Mtb[(size_t)bh * 4096 + p];
  __syncthreads();
  const int l = threadIdx.x & 63, w = threadIdx.x >> 6;
  f4v acc[4];
#pragma unroll
  for (int n = 0; n < 4; ++n) acc[n] = (f4v){0.f, 0.f, 0.f, 0.f};
  const int arow = t0 + w * 16 + (l & 15);
  const int dcol = l & 15;
#pragma unroll
  for (int ks = 0; ks < 2; ++ks) {
    const int k0 = ks * 32 + (l >> 4) * 8;
    s8v af, bf4[4];
    af = *(const s8v*)&timeqb[(size_t)arow * DD + h * DHH + k0];
#pragma unroll
    for (int n = 0; n < 4; ++n)
      bf4[n] = *(const s8v*)&Ms[(dcol + n * 16) * 72 + k0];
#pragma unroll
    for (int n = 0; n < 4; ++n)
      acc[n] = __builtin_amdgcn_mfma_f32_16x16x32_bf16(af, bf4[n], acc[n], 0, 0, 0);
  }
  const int trow = t0 + w * 16 + (l >> 4) * 4;
  float qs[4];
#pragma unroll
  for (int r = 0; r < 4; ++r)
    qs[r] = qsum[(b * TT + trow + r) * HH + h];
#pragma unroll
  for (int n = 0; n < 4; ++n)
#pragma unroll
    for (int r = 0; r < 4; ++r) {
      int i = b * TT + trow + r;
      int col = h * DHH + n * 16 + (l & 15);
      loading[(size_t)i * DD + swz_col(i, col)] = f2bf(qs[r] * acc[n][r]);
    }
}

// ------ gemm_out: 64x64 tiles, 768 blocks (3/CU); 3-buf single-barrier ------
__global__ __launch_bounds__(256) void gemm_out(
    const u16* __restrict__ A, const u16* __restrict__ B, float* __restrict__ C,
    const float* __restrict__ bias, const float* __restrict__ res) {
  __shared__ __align__(16) u16 As[3][2048];
  __shared__ __align__(16) u16 Bs[3][2048];
  const int tid = threadIdx.x;
  const int l = tid & 63;
  const int w = tid >> 6;
  const int wr = w >> 1, wc = w & 1;
  const int i0 = blockIdx.y * 64, j0 = blockIdx.x * 64;
  const int srow = tid >> 2, scol = (tid & 3) * 8;
  const u16* gA0 = A + (size_t)(i0 + srow) * 768 + scol;
  const u16* gB0 = B + (size_t)(j0 + srow) * 768 + scol;
  const int lo = tid * 8;
  f4v acc[2][2];
#pragma unroll
  for (int m = 0; m < 2; ++m)
#pragma unroll
    for (int n = 0; n < 2; ++n) acc[m][n] = (f4v){0.f, 0.f, 0.f, 0.f};

#define STAGE2(kt, b)                 \
  do {                                \
    int kb_ = (kt) << 5;              \
    gload16(gA0 + kb_, &As[b][lo]);   \
    gload16(gB0 + kb_, &Bs[b][lo]);   \
  } while (0)

  STAGE2(0, 0);
  STAGE2(1, 1);
  int aoff[2], boff[2];
#pragma unroll
  for (int m = 0; m < 2; ++m) {
    int row = wr * 32 + (l & 15) + m * 16;
    aoff[m] = row * 32 + (((l >> 4) ^ ((row >> 1) & 3)) << 3);
  }
#pragma unroll
  for (int n = 0; n < 2; ++n) {
    int row = wc * 32 + (l & 15) + n * 16;
    boff[n] = row * 32 + (((l >> 4) ^ ((row >> 1) & 3)) << 3);
  }
  int cb = 0;
  for (int kt = 0; kt < 24; ++kt) {
    if (kt < 23) wait_vm2();
    else wait_vm0();
    raw_barrier();
    if (kt + 2 < 24) STAGE2(kt + 2, (cb + 2) % 3);
    s8v af[2], bf4[2];
#pragma unroll
    for (int m = 0; m < 2; ++m) af[m] = *(const s8v*)&As[cb][aoff[m]];
#pragma unroll
    for (int n = 0; n < 2; ++n) bf4[n] = *(const s8v*)&Bs[cb][boff[n]];
#pragma unroll
    for (int m = 0; m < 2; ++m)
#pragma unroll
      for (int n = 0; n < 2; ++n)
        acc[m][n] =
            __builtin_amdgcn_mfma_f32_16x16x32_bf16(af[m], bf4[n], acc[m][n], 0, 0, 0);
    cb = (cb == 2) ? 0 : cb + 1;
  }
  const int crow = i0 + wr * 32 + (l >> 4) * 4;
  const int ccol = j0 + wc * 32 + (l & 15);
#pragma unroll
  for (int m = 0; m < 2; ++m)
#pragma unroll
    for (int n = 0; n < 2; ++n) {
      int col = ccol + n * 16;
      size_t base = (size_t)(crow + m * 16) * 768 + col;
#pragma unroll
      for (int r = 0; r < 4; ++r)
        C[base + (size_t)r * 768] =
            acc[m][n][r] + bias[col] + res[base + (size_t)r * 768];
    }
}

// ---------------- LayerNorm ----------------
__global__ __launch_bounds__(256) void layernorm(
    const float* __restrict__ X, const float* __restrict__ gamma,
    const float* __restrict__ beta, float* __restrict__ out) {
  int i = blockIdx.x;
  const float* x = X + (size_t)i * 768;
  float vals[3];
  float s = 0.f, s2 = 0.f;
#pragma unroll
  for (int p = 0; p < 3; ++p) {
    float v = x[threadIdx.x + 256 * p];
    vals[p] = v;
    s += v;
    s2 += v * v;
  }
  s = wave_sum(s);
  s2 = wave_sum(s2);
  __shared__ float red[8];
  int w = threadIdx.x >> 6;
  if ((threadIdx.x & 63) == 0) {
    red[w] = s;
    red[4 + w] = s2;
  }
  __syncthreads();
  float stot = red[0] + red[1] + red[2] + red[3];
  float s2tot = red[4] + red[5] + red[6] + red[7];
  float mu = stot * (1.f / 768.f);
  float var = s2tot * (1.f / 768.f) - mu * mu;
  float rs = rsqrtf(var + 1e-5f);
#pragma unroll
  for (int p = 0; p < 3; ++p) {
    int j = threadIdx.x + 256 * p;
    out[(size_t)i * 768 + j] = (vals[p] - mu) * rs * gamma[j] + beta[j];
  }
}

extern "C" void kernel_launch(void* const* d_in, const int* in_sizes, int n_in,
                              void* d_out, int out_size, void* d_ws,
                              size_t ws_size, hipStream_t stream) {
  const float* states = (const float*)d_in[0];
  const int* amask    = (const int*)d_in[1];
  const float* Wq     = (const float*)d_in[2];
  const float* Wk     = (const float*)d_in[3];
  const float* bk     = (const float*)d_in[4];
  const float* Wv     = (const float*)d_in[5];
  const float* bv     = (const float*)d_in[6];
  const float* Wo     = (const float*)d_in[7];
  const float* bo     = (const float*)d_in[8];
  const float* qb     = (const float*)d_in[9];
  const float* tang   = (const float*)d_in[10];
  const float* hdelta = (const float*)d_in[11];
  const float* gamma  = (const float*)d_in[12];
  const float* beta   = (const float*)d_in[13];
  float* out = (float*)d_out;
  float* ws = (float*)d_ws;

  // workspace (float-unit offsets; ~49 MB total)
  u16* timeqb = (u16*)(ws + 0);          // 786432 f
  u16* timekb = (u16*)(ws + 786432);     // 786432 f
  u16* Abf    = (u16*)(ws + 1572864);    // 1572864 f
  u16* Wqb    = (u16*)(ws + 3145728);    // 294912 f
  u16* Wkvb   = (u16*)(ws + 3440640);    // 589824 f
  u16* Wob    = (u16*)(ws + 4030464);    // 294912 f
  float* qsum = ws + 4325376;            // 49152 f
  u16* kvb    = (u16*)(ws + 4374528);    // 786432 f
  float* Mpart= ws + 5160960;            // 3145728 f (32 splits)
  u16* Mtb    = (u16*)(ws + 8306688);    // 24576 f
  u16* loadb  = (u16*)(ws + 8331264);    // 786432 f
  float* xbuf = ws + 9117696;            // 3145728 f

  prep<<<5568, 256, 0, stream>>>(tang, hdelta, states, Wq, Wk, Wv, Wo, timeqb,
                                 timekb, Abf, Wqb, Wkvb, Wob);
  gemm_qkv_fused<<<dim3(18, 64), 256, 0, stream>>>(Abf, Wqb, Wkvb, qb, bk, bv,
                                                   amask, qsum, kvb);
  calc_M<<<768, 256, 0, stream>>>(timekb, kvb, Mpart);
  reduce_M<<<384, 256, 0, stream>>>(Mpart, Mtb);
  calc_loading_mfma<<<dim3(32, 24), 256, 0, stream>>>(timeqb, Mtb, qsum, loadb);
  gemm_out<<<dim3(12, 64), 256, 0, stream>>>(loadb, Wob, xbuf, bo, states);
  layernorm<<<4096, 256, 0, stream>>>(xbuf, gamma, beta, out);
}

// Round 18
// 90.493 us; speedup vs baseline: 1.1304x; 1.0109x over previous
//
#include <hip/hip_runtime.h>
#include <math.h>
#include <stdint.h>

#define TT 2048
#define BB 2
#define DD 768
#define HH 12
#define DHH 64
#define DTT 32
#define NROW 4096  // B*T

typedef float v4 __attribute__((ext_vector_type(4)));
typedef __attribute__((ext_vector_type(8))) short s8v;      // 8 bf16 (4 VGPRs)
typedef __attribute__((ext_vector_type(4))) float f4v;      // MFMA acc
typedef unsigned short u16;
typedef __attribute__((ext_vector_type(4))) unsigned short us4;

__device__ __forceinline__ u16 f2bf(float x) {
  unsigned u = __builtin_bit_cast(unsigned, x);
  u += 0x7fffu + ((u >> 16) & 1u);
  return (u16)(u >> 16);
}
__device__ __forceinline__ float bf2f(u16 b) {
  return __builtin_bit_cast(float, (unsigned)b << 16);
}
__device__ __forceinline__ float wave_sum(float v) {
#pragma unroll
  for (int m = 32; m > 0; m >>= 1) v += __shfl_xor(v, m, 64);
  return v;
}
__device__ __forceinline__ void gload16(const void* g, void* l) {
  __builtin_amdgcn_global_load_lds(
      (const __attribute__((address_space(1))) unsigned int*)g,
      (__attribute__((address_space(3))) unsigned int*)l, 16, 0, 0);
}
// counted waits + raw barrier (no vmcnt(0) drain mid-loop)
__device__ __forceinline__ void wait_vm3() {
  asm volatile("s_waitcnt vmcnt(3)" ::: "memory");
  __builtin_amdgcn_sched_barrier(0);
}
__device__ __forceinline__ void wait_vm2() {
  asm volatile("s_waitcnt vmcnt(2)" ::: "memory");
  __builtin_amdgcn_sched_barrier(0);
}
__device__ __forceinline__ void wait_vm0() {
  asm volatile("s_waitcnt vmcnt(0)" ::: "memory");
  __builtin_amdgcn_sched_barrier(0);
}
__device__ __forceinline__ void raw_barrier() {
  asm volatile("s_barrier" ::: "memory");
}
// 16B-chunk swizzle within a row's 64B k-tile group: chunk ^= (row>>1)&3.
// Stored pre-swizzled in global; ds_read applies the same XOR (involution).
__device__ __forceinline__ int swz_col(int row, int col) {
  int ch = (col >> 3) & 3;
  return (col & ~24) | (((ch ^ ((row >> 1) & 3)) & 3) << 3);
}

// ------ prep: time tables (recurrence) + swizzled f32->bf16 conversions -----
__global__ __launch_bounds__(256) void prep(
    const float* __restrict__ tang, const float* __restrict__ hdelta,
    const float* __restrict__ s, const float* __restrict__ wq,
    const float* __restrict__ wk, const float* __restrict__ wv,
    const float* __restrict__ wo, u16* __restrict__ timeqb,
    u16* __restrict__ timekb, u16* __restrict__ sb, u16* __restrict__ wqb,
    u16* __restrict__ wkvb, u16* __restrict__ wob) {
  int bid = blockIdx.x;
  if (bid < 192) {
    // one thread per (h,d,16-t chunk); 3 sincosf + 15 rotations
    int idx = bid * 256 + threadIdx.x;  // 49152
    int d = idx & 31;
    int h = (idx >> 5) % HH;
    int tc = idx / (32 * HH);           // 0..127
    int t0 = tc * 16;
    float ang = tang[h * DTT + d];
    float ca, sa;
    sincosf(ang, &sa, &ca);
    float ck, sk, cq, sq;
    sincosf((float)t0 * ang, &sk, &ck);
    sincosf(((float)t0 + hdelta[h]) * ang, &sq, &cq);
#pragma unroll
    for (int j = 0; j < 16; ++j) {
      int t = t0 + j;
      timekb[t * DD + h * DHH + d]       = f2bf((ck + sk) * 0.125f);
      timekb[t * DD + h * DHH + d + DTT] = f2bf((ck - sk) * 0.125f);
      timeqb[t * DD + h * DHH + d]       = f2bf((cq + sq) * 0.125f);
      timeqb[t * DD + h * DHH + d + DTT] = f2bf((cq - sq) * 0.125f);
      float ck2 = ck * ca - sk * sa;
      sk = sk * ca + ck * sa;
      ck = ck2;
      float cq2 = cq * ca - sq * sa;
      sq = sq * ca + cq * sa;
      cq = cq2;
    }
    return;
  }
  int idx = (bid - 192) * 256 + threadIdx.x;
  int off = idx * 4;
  const float* src;
  u16* dst;
  int so, rr, cc;
  if (off < 3145728) {                      // states -> Abf (swizzled)
    src = s; dst = sb; so = off; rr = so / 768; cc = so % 768;
  } else if (off < 3735552) {               // Wq (swizzled)
    src = wq; dst = wqb; so = off - 3145728; rr = so / 768; cc = so % 768;
  } else if (off < 4325376) {               // Wk -> head-major + swizzle
    src = wk; so = off - 3735552;
    int j = so / 768; cc = so - j * 768;
    int h = j >> 6, r = j & 63;
    dst = wkvb; rr = h * 128 + r;
  } else if (off < 4915200) {               // Wv -> head-major + swizzle
    src = wv; so = off - 4325376;
    int j = so / 768; cc = so - j * 768;
    int h = j >> 6, r = j & 63;
    dst = wkvb; rr = h * 128 + 64 + r;
  } else {                                  // Wo (swizzled)
    src = wo; dst = wob; so = off - 4915200; rr = so / 768; cc = so % 768;
  }
  int dof = rr * 768 + swz_col(rr, cc);
  v4 f = *(const v4*)&src[so];
  us4 o;
#pragma unroll
  for (int j = 0; j < 4; ++j) o[j] = f2bf(f[j]);
  *(us4*)&dst[dof] = o;
}

// ---- gemm_qkv_fused: 64x128 tiles, 1152 blocks; 2-buf double-barrier pipe
// (round-10 optimum: 25KB LDS -> 6 blocks/CU, all co-resident).
// bx<6: Q-region -> qsum epilogue. bx in [6,18): head = bx-6 -> softmax(K)*V.
__global__ __launch_bounds__(256) void gemm_qkv_fused(
    const u16* __restrict__ A, const u16* __restrict__ Wqb,
    const u16* __restrict__ Wkvb, const float* __restrict__ qb,
    const float* __restrict__ bk, const float* __restrict__ bv,
    const int* __restrict__ amask, float* __restrict__ qsum,
    u16* __restrict__ kvb) {
  __shared__ __align__(16) u16 As[2][2176];  // A 64x32/buf; both bufs = P 64x68
  __shared__ __align__(16) u16 Bs[2][4096];  // B 128x32/buf
  const int tid = threadIdx.x;
  const int l = tid & 63;
  const int w = tid >> 6;
  const int wr = w >> 1, wc = w & 1;
  const int bx = blockIdx.x;
  const bool isQ = bx < 6;
  const int i0 = blockIdx.y * 64;
  const u16* Bbase = isQ ? (Wqb + (size_t)bx * 128 * 768)
                         : (Wkvb + (size_t)(bx - 6) * 128 * 768);
  const int srow = tid >> 2, scol = (tid & 3) * 8;
  const u16* gA0 = A + (size_t)(i0 + srow) * 768 + scol;   // 64 rows
  const u16* gB0 = Bbase + (size_t)srow * 768 + scol;      // rows 0-63
  const u16* gB1 = gB0 + (size_t)64 * 768;                 // rows 64-127
  const int lo = tid * 8;
  f4v acc[2][4];
#pragma unroll
  for (int m = 0; m < 2; ++m)
#pragma unroll
    for (int n = 0; n < 4; ++n) acc[m][n] = (f4v){0.f, 0.f, 0.f, 0.f};

#define STAGE(kt, b)                       \
  do {                                     \
    int kb_ = (kt) << 5;                   \
    gload16(gA0 + kb_, &As[b][lo]);        \
    gload16(gB0 + kb_, &Bs[b][lo]);        \
    gload16(gB1 + kb_, &Bs[b][2048 + lo]); \
  } while (0)

  STAGE(0, 0);
  STAGE(1, 1);
  // swizzled, loop-invariant frag addresses
  int aoff[2], boff[4];
#pragma unroll
  for (int m = 0; m < 2; ++m) {
    int row = wr * 32 + (l & 15) + m * 16;
    aoff[m] = row * 32 + (((l >> 4) ^ ((row >> 1) & 3)) << 3);
  }
#pragma unroll
  for (int n = 0; n < 4; ++n) {
    int row = wc * 64 + (l & 15) + n * 16;
    boff[n] = row * 32 + (((l >> 4) ^ ((row >> 1) & 3)) << 3);
  }
  int cb = 0;
  for (int kt = 0; kt < 24; ++kt) {
    if (kt < 23) wait_vm3();          // tile kt's own 3 loads done
    else wait_vm0();
    raw_barrier();                    // all waves' tile-kt portions landed
    s8v af[2], bf4[4];
#pragma unroll
    for (int m = 0; m < 2; ++m) af[m] = *(const s8v*)&As[cb][aoff[m]];
#pragma unroll
    for (int n = 0; n < 4; ++n) bf4[n] = *(const s8v*)&Bs[cb][boff[n]];
#pragma unroll
    for (int m = 0; m < 2; ++m)
#pragma unroll
      for (int n = 0; n < 4; ++n)
        acc[m][n] =
            __builtin_amdgcn_mfma_f32_16x16x32_bf16(af[m], bf4[n], acc[m][n], 0, 0, 0);
    raw_barrier();                    // all waves consumed buf cb
    if (kt + 2 < 24) STAGE(kt + 2, cb);  // restage just-read buf
    cb ^= 1;
  }
  __syncthreads();  // drain before LDS reuse in epilogue

  const int crow = i0 + wr * 32 + (l >> 4) * 4;
  if (isQ) {
    const int head = bx * 2 + wc;
    float eqb[4];
#pragma unroll
    for (int n = 0; n < 4; ++n)
      eqb[n] = expf(qb[head * 64 + n * 16 + (l & 15)]);
#pragma unroll
    for (int m = 0; m < 2; ++m)
#pragma unroll
      for (int r = 0; r < 4; ++r) {
        float ssum = 0.f;
#pragma unroll
        for (int n = 0; n < 4; ++n)
          ssum += 1.f / (1.f + expf(-(acc[m][n][r] - eqb[n])));
#pragma unroll
        for (int mm = 8; mm > 0; mm >>= 1) ssum += __shfl_xor(ssum, mm, 64);
        int row = crow + m * 16 + r;
        if ((l & 15) == 0)
          qsum[row * HH + head] = ssum * (float)amask[row] * (1.f / 64.f);
      }
  } else {
    const int head = bx - 6;
    u16* Ps = &As[0][0];  // 64 rows x stride 68 = 4352 u16 (both A bufs)
    if (wc == 0) {        // K columns -> row softmax -> P to LDS
#pragma unroll
      for (int m = 0; m < 2; ++m)
#pragma unroll
        for (int r = 0; r < 4; ++r) {
          int row = crow + m * 16 + r;
          float mk = (float)amask[row];
          float kv4[4];
#pragma unroll
          for (int n = 0; n < 4; ++n)
            kv4[n] = (acc[m][n][r] + bk[head * 64 + n * 16 + (l & 15)]) * mk;
          float mx = fmaxf(fmaxf(kv4[0], kv4[1]), fmaxf(kv4[2], kv4[3]));
#pragma unroll
          for (int mm = 8; mm > 0; mm >>= 1)
            mx = fmaxf(mx, __shfl_xor(mx, mm, 64));
          float e[4], es = 0.f;
#pragma unroll
          for (int n = 0; n < 4; ++n) { e[n] = expf(kv4[n] - mx); es += e[n]; }
#pragma unroll
          for (int mm = 8; mm > 0; mm >>= 1) es += __shfl_xor(es, mm, 64);
          float inv = 1.f / es;
          int lrow = wr * 32 + (l >> 4) * 4 + m * 16 + r;
#pragma unroll
          for (int n = 0; n < 4; ++n)
            Ps[lrow * 68 + n * 16 + (l & 15)] = f2bf(e[n] * inv);
        }
    }
    __syncthreads();
    if (wc == 1) {  // V columns: kv = P * V -> bf16
#pragma unroll
      for (int m = 0; m < 2; ++m)
#pragma unroll
        for (int r = 0; r < 4; ++r) {
          int row = crow + m * 16 + r;
          int lrow = wr * 32 + (l >> 4) * 4 + m * 16 + r;
#pragma unroll
          for (int n = 0; n < 4; ++n) {
            int d = n * 16 + (l & 15);
            float p = bf2f(Ps[lrow * 68 + d]);
            float vv = acc[m][n][r] + bv[head * 64 + d];
            kvb[((size_t)row * HH + head) * 64 + d] = f2bf(p * vv);
          }
        }
    }
  }
}

// --- Mpart[blk][d][r] over 64-t slices (32 splits, 768 blocks, bf16 in) ------
__global__ __launch_bounds__(256) void calc_M(
    const u16* __restrict__ timekb, const u16* __restrict__ kvb,
    float* __restrict__ Mpart) {
  int blk = blockIdx.x;  // bh*32 + split
  int split = blk & 31;
  int bh = blk >> 5;
  int b = bh / HH, h = bh % HH;
  __shared__ float Tk[64][68];
  __shared__ float Kv[64][68];
  int tid = threadIdx.x;
  int tx = tid & 15, ty = tid >> 4;
  float acc[4][4] = {};
  int t0 = split * 64;
#pragma unroll
  for (int p = 0; p < 4; ++p) {
    int f = tid + 256 * p;
    int r = f >> 4, c4 = (f & 15) << 2;
    int t = t0 + r;
    us4 tk = *(const us4*)&timekb[(size_t)t * DD + h * DHH + c4];
    us4 kv = *(const us4*)&kvb[((size_t)(b * TT + t) * HH + h) * 64 + c4];
#pragma unroll
    for (int j = 0; j < 4; ++j) {
      Tk[r][c4 + j] = bf2f(tk[j]);
      Kv[r][c4 + j] = bf2f(kv[j]);
    }
  }
  __syncthreads();
#pragma unroll
  for (int kk = 0; kk < 64; ++kk) {
    v4 a = *(const v4*)&Tk[kk][ty * 4];
    v4 bv4 = *(const v4*)&Kv[kk][tx * 4];
#pragma unroll
    for (int r = 0; r < 4; ++r)
#pragma unroll
      for (int c = 0; c < 4; ++c) acc[r][c] += a[r] * bv4[c];
  }
#pragma unroll
  for (int r = 0; r < 4; ++r)
#pragma unroll
    for (int c = 0; c < 4; ++c)
      Mpart[(size_t)blk * 4096 + (tx * 4 + c) * 64 + (ty * 4 + r)] = acc[r][c];
}

// ------- Mtb[bh][p] = sum_{s<32} Mpart[bh*32+s][p] -> bf16 (fixed order) ------
__global__ __launch_bounds__(256) void reduce_M(
    const float* __restrict__ Mpart, u16* __restrict__ Mtb) {
  int idx = blockIdx.x * 256 + threadIdx.x;
  int bh = idx >> 12;
  int p = idx & 4095;
  float s = 0.f;
#pragma unroll
  for (int sp = 0; sp < 32; ++sp)
    s += Mpart[(size_t)((bh << 5) + sp) * 4096 + p];
  Mtb[(size_t)bh * 4096 + p] = f2bf(s);
}

// ------ loading = qsum * (timeq @ M) via MFMA -> bf16 (PRE-SWIZZLED store) ----
// grid (32, 24): 64-t chunks, each wave 16 rows x 64 cols.
__global__ __launch_bounds__(256) void calc_loading_mfma(
    const u16* __restrict__ timeqb, const u16* __restrict__ Mtb,
    const float* __restrict__ qsum, u16* __restrict__ loading) {
  const int bh = blockIdx.y;
  const int b = bh / HH, h = bh % HH;
  const int t0 = blockIdx.x * 64;
  __shared__ __align__(16) u16 Ms[64 * 72];
  for (int p = threadIdx.x; p < 4096; p += 256)
    Ms[(p >> 6) * 72 + (p & 63)] = Mtb[(size_t)bh * 4096 + p];
  __syncthreads();
  const int l = threadIdx.x & 63, w = threadIdx.x >> 6;
  f4v acc[4];
#pragma unroll
  for (int n = 0; n < 4; ++n) acc[n] = (f4v){0.f, 0.f, 0.f, 0.f};
  const int arow = t0 + w * 16 + (l & 15);
  const int dcol = l & 15;
#pragma unroll
  for (int ks = 0; ks < 2; ++ks) {
    const int k0 = ks * 32 + (l >> 4) * 8;
    s8v af, bf4[4];
    af = *(const s8v*)&timeqb[(size_t)arow * DD + h * DHH + k0];
#pragma unroll
    for (int n = 0; n < 4; ++n)
      bf4[n] = *(const s8v*)&Ms[(dcol + n * 16) * 72 + k0];
#pragma unroll
    for (int n = 0; n < 4; ++n)
      acc[n] = __builtin_amdgcn_mfma_f32_16x16x32_bf16(af, bf4[n], acc[n], 0, 0, 0);
  }
  const int trow = t0 + w * 16 + (l >> 4) * 4;
  float qs[4];
#pragma unroll
  for (int r = 0; r < 4; ++r)
    qs[r] = qsum[(b * TT + trow + r) * HH + h];
#pragma unroll
  for (int n = 0; n < 4; ++n)
#pragma unroll
    for (int r = 0; r < 4; ++r) {
      int i = b * TT + trow + r;
      int col = h * DHH + n * 16 + (l & 15);
      loading[(size_t)i * DD + swz_col(i, col)] = f2bf(qs[r] * acc[n][r]);
    }
}

// ------ gemm_out: 64x64 tiles, 768 blocks (3/CU); 3-buf single-barrier ------
__global__ __launch_bounds__(256) void gemm_out(
    const u16* __restrict__ A, const u16* __restrict__ B, float* __restrict__ C,
    const float* __restrict__ bias, const float* __restrict__ res) {
  __shared__ __align__(16) u16 As[3][2048];
  __shared__ __align__(16) u16 Bs[3][2048];
  const int tid = threadIdx.x;
  const int l = tid & 63;
  const int w = tid >> 6;
  const int wr = w >> 1, wc = w & 1;
  const int i0 = blockIdx.y * 64, j0 = blockIdx.x * 64;
  const int srow = tid >> 2, scol = (tid & 3) * 8;
  const u16* gA0 = A + (size_t)(i0 + srow) * 768 + scol;
  const u16* gB0 = B + (size_t)(j0 + srow) * 768 + scol;
  const int lo = tid * 8;
  f4v acc[2][2];
#pragma unroll
  for (int m = 0; m < 2; ++m)
#pragma unroll
    for (int n = 0; n < 2; ++n) acc[m][n] = (f4v){0.f, 0.f, 0.f, 0.f};

#define STAGE2(kt, b)                 \
  do {                                \
    int kb_ = (kt) << 5;              \
    gload16(gA0 + kb_, &As[b][lo]);   \
    gload16(gB0 + kb_, &Bs[b][lo]);   \
  } while (0)

  STAGE2(0, 0);
  STAGE2(1, 1);
  int aoff[2], boff[2];
#pragma unroll
  for (int m = 0; m < 2; ++m) {
    int row = wr * 32 + (l & 15) + m * 16;
    aoff[m] = row * 32 + (((l >> 4) ^ ((row >> 1) & 3)) << 3);
  }
#pragma unroll
  for (int n = 0; n < 2; ++n) {
    int row = wc * 32 + (l & 15) + n * 16;
    boff[n] = row * 32 + (((l >> 4) ^ ((row >> 1) & 3)) << 3);
  }
  int cb = 0;
  for (int kt = 0; kt < 24; ++kt) {
    if (kt < 23) wait_vm2();
    else wait_vm0();
    raw_barrier();
    if (kt + 2 < 24) STAGE2(kt + 2, (cb + 2) % 3);
    s8v af[2], bf4[2];
#pragma unroll
    for (int m = 0; m < 2; ++m) af[m] = *(const s8v*)&As[cb][aoff[m]];
#pragma unroll
    for (int n = 0; n < 2; ++n) bf4[n] = *(const s8v*)&Bs[cb][boff[n]];
#pragma unroll
    for (int m = 0; m < 2; ++m)
#pragma unroll
      for (int n = 0; n < 2; ++n)
        acc[m][n] =
            __builtin_amdgcn_mfma_f32_16x16x32_bf16(af[m], bf4[n], acc[m][n], 0, 0, 0);
    cb = (cb == 2) ? 0 : cb + 1;
  }
  const int crow = i0 + wr * 32 + (l >> 4) * 4;
  const int ccol = j0 + wc * 32 + (l & 15);
#pragma unroll
  for (int m = 0; m < 2; ++m)
#pragma unroll
    for (int n = 0; n < 2; ++n) {
      int col = ccol + n * 16;
      size_t base = (size_t)(crow + m * 16) * 768 + col;
#pragma unroll
      for (int r = 0; r < 4; ++r)
        C[base + (size_t)r * 768] =
            acc[m][n][r] + bias[col] + res[base + (size_t)r * 768];
    }
}

// ---------------- LayerNorm ----------------
__global__ __launch_bounds__(256) void layernorm(
    const float* __restrict__ X, const float* __restrict__ gamma,
    const float* __restrict__ beta, float* __restrict__ out) {
  int i = blockIdx.x;
  const float* x = X + (size_t)i * 768;
  float vals[3];
  float s = 0.f, s2 = 0.f;
#pragma unroll
  for (int p = 0; p < 3; ++p) {
    float v = x[threadIdx.x + 256 * p];
    vals[p] = v;
    s += v;
    s2 += v * v;
  }
  s = wave_sum(s);
  s2 = wave_sum(s2);
  __shared__ float red[8];
  int w = threadIdx.x >> 6;
  if ((threadIdx.x & 63) == 0) {
    red[w] = s;
    red[4 + w] = s2;
  }
  __syncthreads();
  float stot = red[0] + red[1] + red[2] + red[3];
  float s2tot = red[4] + red[5] + red[6] + red[7];
  float mu = stot * (1.f / 768.f);
  float var = s2tot * (1.f / 768.f) - mu * mu;
  float rs = rsqrtf(var + 1e-5f);
#pragma unroll
  for (int p = 0; p < 3; ++p) {
    int j = threadIdx.x + 256 * p;
    out[(size_t)i * 768 + j] = (vals[p] - mu) * rs * gamma[j] + beta[j];
  }
}

extern "C" void kernel_launch(void* const* d_in, const int* in_sizes, int n_in,
                              void* d_out, int out_size, void* d_ws,
                              size_t ws_size, hipStream_t stream) {
  const float* states = (const float*)d_in[0];
  const int* amask    = (const int*)d_in[1];
  const float* Wq     = (const float*)d_in[2];
  const float* Wk     = (const float*)d_in[3];
  const float* bk     = (const float*)d_in[4];
  const float* Wv     = (const float*)d_in[5];
  const float* bv     = (const float*)d_in[6];
  const float* Wo     = (const float*)d_in[7];
  const float* bo     = (const float*)d_in[8];
  const float* qb     = (const float*)d_in[9];
  const float* tang   = (const float*)d_in[10];
  const float* hdelta = (const float*)d_in[11];
  const float* gamma  = (const float*)d_in[12];
  const float* beta   = (const float*)d_in[13];
  float* out = (float*)d_out;
  float* ws = (float*)d_ws;

  // CORRECTED workspace layout (float-unit offsets, non-overlapping).
  // Root cause of rounds 13/15/16/17 failures: kvb/Mtb/loadb were sized at
  // half their true u16 footprint, aliasing Mpart/loadb/xbuf respectively
  // (always the batch-1 rows -> intermittent batch-1 corruption).
  u16* timeqb = (u16*)(ws + 0);          // 1,572,864 u16 = [0, 786432)
  u16* timekb = (u16*)(ws + 786432);     // 1,572,864 u16 = [786432, 1572864)
  u16* Abf    = (u16*)(ws + 1572864);    // 3,145,728 u16 = [1572864, 3145728)
  u16* Wqb    = (u16*)(ws + 3145728);    //   589,824 u16 = [3145728, 3440640)
  u16* Wkvb   = (u16*)(ws + 3440640);    // 1,179,648 u16 = [3440640, 4030464)
  u16* Wob    = (u16*)(ws + 4030464);    //   589,824 u16 = [4030464, 4325376)
  float* qsum = ws + 4325376;            //    49,152 f   = [4325376, 4374528)
  u16* kvb    = (u16*)(ws + 4374528);    // 3,145,728 u16 = [4374528, 5947392)
  float* Mpart= ws + 5947392;            // 3,145,728 f   = [5947392, 9093120)
  u16* Mtb    = (u16*)(ws + 9093120);    //    98,304 u16 = [9093120, 9142272)
  u16* loadb  = (u16*)(ws + 9142272);    // 3,145,728 u16 = [9142272, 10715136)
  float* xbuf = ws + 10715136;           // 3,145,728 f   = [10715136, 13860864)

  prep<<<5568, 256, 0, stream>>>(tang, hdelta, states, Wq, Wk, Wv, Wo, timeqb,
                                 timekb, Abf, Wqb, Wkvb, Wob);
  gemm_qkv_fused<<<dim3(18, 64), 256, 0, stream>>>(Abf, Wqb, Wkvb, qb, bk, bv,
                                                   amask, qsum, kvb);
  calc_M<<<768, 256, 0, stream>>>(timekb, kvb, Mpart);
  reduce_M<<<384, 256, 0, stream>>>(Mpart, Mtb);
  calc_loading_mfma<<<dim3(32, 24), 256, 0, stream>>>(timeqb, Mtb, qsum, loadb);
  gemm_out<<<dim3(12, 64), 256, 0, stream>>>(loadb, Wob, xbuf, bo, states);
  layernorm<<<4096, 256, 0, stream>>>(xbuf, gamma, beta, out);
}

// Round 19
// 88.977 us; speedup vs baseline: 1.1497x; 1.0170x over previous
//
#include <hip/hip_runtime.h>
#include <math.h>
#include <stdint.h>

#define TT 2048
#define BB 2
#define DD 768
#define HH 12
#define DHH 64
#define DTT 32
#define NROW 4096  // B*T

typedef float v4 __attribute__((ext_vector_type(4)));
typedef __attribute__((ext_vector_type(8))) short s8v;      // 8 bf16 (4 VGPRs)
typedef __attribute__((ext_vector_type(4))) float f4v;      // MFMA acc
typedef unsigned short u16;
typedef __attribute__((ext_vector_type(4))) unsigned short us4;

__device__ __forceinline__ u16 f2bf(float x) {
  unsigned u = __builtin_bit_cast(unsigned, x);
  u += 0x7fffu + ((u >> 16) & 1u);
  return (u16)(u >> 16);
}
__device__ __forceinline__ float bf2f(u16 b) {
  return __builtin_bit_cast(float, (unsigned)b << 16);
}
__device__ __forceinline__ float wave_sum(float v) {
#pragma unroll
  for (int m = 32; m > 0; m >>= 1) v += __shfl_xor(v, m, 64);
  return v;
}
__device__ __forceinline__ void gload16(const void* g, void* l) {
  __builtin_amdgcn_global_load_lds(
      (const __attribute__((address_space(1))) unsigned int*)g,
      (__attribute__((address_space(3))) unsigned int*)l, 16, 0, 0);
}
// counted waits + raw barrier (no vmcnt(0) drain mid-loop)
__device__ __forceinline__ void wait_vm3() {
  asm volatile("s_waitcnt vmcnt(3)" ::: "memory");
  __builtin_amdgcn_sched_barrier(0);
}
__device__ __forceinline__ void wait_vm2() {
  asm volatile("s_waitcnt vmcnt(2)" ::: "memory");
  __builtin_amdgcn_sched_barrier(0);
}
__device__ __forceinline__ void wait_vm0() {
  asm volatile("s_waitcnt vmcnt(0)" ::: "memory");
  __builtin_amdgcn_sched_barrier(0);
}
__device__ __forceinline__ void raw_barrier() {
  asm volatile("s_barrier" ::: "memory");
}
// 16B-chunk swizzle within a row's 64B k-tile group: chunk ^= (row>>1)&3.
// Stored pre-swizzled in global; ds_read applies the same XOR (involution).
__device__ __forceinline__ int swz_col(int row, int col) {
  int ch = (col >> 3) & 3;
  return (col & ~24) | (((ch ^ ((row >> 1) & 3)) & 3) << 3);
}

// ------ prep: time tables (recurrence) + swizzled f32->bf16 conversions -----
__global__ __launch_bounds__(256) void prep(
    const float* __restrict__ tang, const float* __restrict__ hdelta,
    const float* __restrict__ s, const float* __restrict__ wq,
    const float* __restrict__ wk, const float* __restrict__ wv,
    const float* __restrict__ wo, u16* __restrict__ timeqb,
    u16* __restrict__ timekb, u16* __restrict__ sb, u16* __restrict__ wqb,
    u16* __restrict__ wkvb, u16* __restrict__ wob) {
  int bid = blockIdx.x;
  if (bid < 192) {
    // one thread per (h,d,16-t chunk); 3 sincosf + 15 rotations
    int idx = bid * 256 + threadIdx.x;  // 49152
    int d = idx & 31;
    int h = (idx >> 5) % HH;
    int tc = idx / (32 * HH);           // 0..127
    int t0 = tc * 16;
    float ang = tang[h * DTT + d];
    float ca, sa;
    sincosf(ang, &sa, &ca);
    float ck, sk, cq, sq;
    sincosf((float)t0 * ang, &sk, &ck);
    sincosf(((float)t0 + hdelta[h]) * ang, &sq, &cq);
#pragma unroll
    for (int j = 0; j < 16; ++j) {
      int t = t0 + j;
      timekb[t * DD + h * DHH + d]       = f2bf((ck + sk) * 0.125f);
      timekb[t * DD + h * DHH + d + DTT] = f2bf((ck - sk) * 0.125f);
      timeqb[t * DD + h * DHH + d]       = f2bf((cq + sq) * 0.125f);
      timeqb[t * DD + h * DHH + d + DTT] = f2bf((cq - sq) * 0.125f);
      float ck2 = ck * ca - sk * sa;
      sk = sk * ca + ck * sa;
      ck = ck2;
      float cq2 = cq * ca - sq * sa;
      sq = sq * ca + cq * sa;
      cq = cq2;
    }
    return;
  }
  int idx = (bid - 192) * 256 + threadIdx.x;
  int off = idx * 4;
  const float* src;
  u16* dst;
  int so, rr, cc;
  if (off < 3145728) {                      // states -> Abf (swizzled)
    src = s; dst = sb; so = off; rr = so / 768; cc = so % 768;
  } else if (off < 3735552) {               // Wq (swizzled)
    src = wq; dst = wqb; so = off - 3145728; rr = so / 768; cc = so % 768;
  } else if (off < 4325376) {               // Wk -> head-major + swizzle
    src = wk; so = off - 3735552;
    int j = so / 768; cc = so - j * 768;
    int h = j >> 6, r = j & 63;
    dst = wkvb; rr = h * 128 + r;
  } else if (off < 4915200) {               // Wv -> head-major + swizzle
    src = wv; so = off - 4325376;
    int j = so / 768; cc = so - j * 768;
    int h = j >> 6, r = j & 63;
    dst = wkvb; rr = h * 128 + 64 + r;
  } else {                                  // Wo (swizzled)
    src = wo; dst = wob; so = off - 4915200; rr = so / 768; cc = so % 768;
  }
  int dof = rr * 768 + swz_col(rr, cc);
  v4 f = *(const v4*)&src[so];
  us4 o;
#pragma unroll
  for (int j = 0; j < 4; ++j) o[j] = f2bf(f[j]);
  *(us4*)&dst[dof] = o;
}

// ---- gemm_qkv_fused: 64x128 tiles, 1152 blocks; 2-buf double-barrier pipe
// (round-10 optimum: 25KB LDS -> 6 blocks/CU, all co-resident).
// XCD 2D tiling (speed-only bijective remap): XCD x owns a 9(bx) x 16(by)
// rectangle -> per-XCD L2 set = 9 B-panels (1.8MB) + 16 A-panels (1.6MB)
// = 3.4MB < 4MB L2. Assumes HW round-robin xcd = lid%8.
// bx<6: Q-region -> qsum epilogue. bx in [6,18): head = bx-6 -> softmax(K)*V.
__global__ __launch_bounds__(256) void gemm_qkv_fused(
    const u16* __restrict__ A, const u16* __restrict__ Wqb,
    const u16* __restrict__ Wkvb, const float* __restrict__ qb,
    const float* __restrict__ bk, const float* __restrict__ bv,
    const int* __restrict__ amask, float* __restrict__ qsum,
    u16* __restrict__ kvb) {
  __shared__ __align__(16) u16 As[2][2176];  // A 64x32/buf; both bufs = P 64x68
  __shared__ __align__(16) u16 Bs[2][4096];  // B 128x32/buf
  const int tid = threadIdx.x;
  const int l = tid & 63;
  const int w = tid >> 6;
  const int wr = w >> 1, wc = w & 1;
  // bijective XCD decode: x = lid&7 picks the 9x16 tile; t indexes within.
  const int lid = blockIdx.x;
  const int x = lid & 7;
  const int t = lid >> 3;               // 0..143
  const int bx = (t % 9) + 9 * (x & 1);
  const int by = (t / 9) + 16 * (x >> 1);
  const bool isQ = bx < 6;
  const int i0 = by * 64;
  const u16* Bbase = isQ ? (Wqb + (size_t)bx * 128 * 768)
                         : (Wkvb + (size_t)(bx - 6) * 128 * 768);
  const int srow = tid >> 2, scol = (tid & 3) * 8;
  const u16* gA0 = A + (size_t)(i0 + srow) * 768 + scol;   // 64 rows
  const u16* gB0 = Bbase + (size_t)srow * 768 + scol;      // rows 0-63
  const u16* gB1 = gB0 + (size_t)64 * 768;                 // rows 64-127
  const int lo = tid * 8;
  f4v acc[2][4];
#pragma unroll
  for (int m = 0; m < 2; ++m)
#pragma unroll
    for (int n = 0; n < 4; ++n) acc[m][n] = (f4v){0.f, 0.f, 0.f, 0.f};

#define STAGE(kt, b)                       \
  do {                                     \
    int kb_ = (kt) << 5;                   \
    gload16(gA0 + kb_, &As[b][lo]);        \
    gload16(gB0 + kb_, &Bs[b][lo]);        \
    gload16(gB1 + kb_, &Bs[b][2048 + lo]); \
  } while (0)

  STAGE(0, 0);
  STAGE(1, 1);
  // swizzled, loop-invariant frag addresses
  int aoff[2], boff[4];
#pragma unroll
  for (int m = 0; m < 2; ++m) {
    int row = wr * 32 + (l & 15) + m * 16;
    aoff[m] = row * 32 + (((l >> 4) ^ ((row >> 1) & 3)) << 3);
  }
#pragma unroll
  for (int n = 0; n < 4; ++n) {
    int row = wc * 64 + (l & 15) + n * 16;
    boff[n] = row * 32 + (((l >> 4) ^ ((row >> 1) & 3)) << 3);
  }
  int cb = 0;
  for (int kt = 0; kt < 24; ++kt) {
    if (kt < 23) wait_vm3();          // tile kt's own 3 loads done
    else wait_vm0();
    raw_barrier();                    // all waves' tile-kt portions landed
    s8v af[2], bf4[4];
#pragma unroll
    for (int m = 0; m < 2; ++m) af[m] = *(const s8v*)&As[cb][aoff[m]];
#pragma unroll
    for (int n = 0; n < 4; ++n) bf4[n] = *(const s8v*)&Bs[cb][boff[n]];
#pragma unroll
    for (int m = 0; m < 2; ++m)
#pragma unroll
      for (int n = 0; n < 4; ++n)
        acc[m][n] =
            __builtin_amdgcn_mfma_f32_16x16x32_bf16(af[m], bf4[n], acc[m][n], 0, 0, 0);
    raw_barrier();                    // all waves consumed buf cb
    if (kt + 2 < 24) STAGE(kt + 2, cb);  // restage just-read buf
    cb ^= 1;
  }
  __syncthreads();  // drain before LDS reuse in epilogue

  const int crow = i0 + wr * 32 + (l >> 4) * 4;
  if (isQ) {
    const int head = bx * 2 + wc;
    float eqb[4];
#pragma unroll
    for (int n = 0; n < 4; ++n)
      eqb[n] = expf(qb[head * 64 + n * 16 + (l & 15)]);
#pragma unroll
    for (int m = 0; m < 2; ++m)
#pragma unroll
      for (int r = 0; r < 4; ++r) {
        float ssum = 0.f;
#pragma unroll
        for (int n = 0; n < 4; ++n)
          ssum += 1.f / (1.f + expf(-(acc[m][n][r] - eqb[n])));
#pragma unroll
        for (int mm = 8; mm > 0; mm >>= 1) ssum += __shfl_xor(ssum, mm, 64);
        int row = crow + m * 16 + r;
        if ((l & 15) == 0)
          qsum[row * HH + head] = ssum * (float)amask[row] * (1.f / 64.f);
      }
  } else {
    const int head = bx - 6;
    u16* Ps = &As[0][0];  // 64 rows x stride 68 = 4352 u16 (both A bufs)
    if (wc == 0) {        // K columns -> row softmax -> P to LDS
#pragma unroll
      for (int m = 0; m < 2; ++m)
#pragma unroll
        for (int r = 0; r < 4; ++r) {
          int row = crow + m * 16 + r;
          float mk = (float)amask[row];
          float kv4[4];
#pragma unroll
          for (int n = 0; n < 4; ++n)
            kv4[n] = (acc[m][n][r] + bk[head * 64 + n * 16 + (l & 15)]) * mk;
          float mx = fmaxf(fmaxf(kv4[0], kv4[1]), fmaxf(kv4[2], kv4[3]));
#pragma unroll
          for (int mm = 8; mm > 0; mm >>= 1)
            mx = fmaxf(mx, __shfl_xor(mx, mm, 64));
          float e[4], es = 0.f;
#pragma unroll
          for (int n = 0; n < 4; ++n) { e[n] = expf(kv4[n] - mx); es += e[n]; }
#pragma unroll
          for (int mm = 8; mm > 0; mm >>= 1) es += __shfl_xor(es, mm, 64);
          float inv = 1.f / es;
          int lrow = wr * 32 + (l >> 4) * 4 + m * 16 + r;
#pragma unroll
          for (int n = 0; n < 4; ++n)
            Ps[lrow * 68 + n * 16 + (l & 15)] = f2bf(e[n] * inv);
        }
    }
    __syncthreads();
    if (wc == 1) {  // V columns: kv = P * V -> bf16
#pragma unroll
      for (int m = 0; m < 2; ++m)
#pragma unroll
        for (int r = 0; r < 4; ++r) {
          int row = crow + m * 16 + r;
          int lrow = wr * 32 + (l >> 4) * 4 + m * 16 + r;
#pragma unroll
          for (int n = 0; n < 4; ++n) {
            int d = n * 16 + (l & 15);
            float p = bf2f(Ps[lrow * 68 + d]);
            float vv = acc[m][n][r] + bv[head * 64 + d];
            kvb[((size_t)row * HH + head) * 64 + d] = f2bf(p * vv);
          }
        }
    }
  }
}

// --- Mpart[blk][d][r] over 64-t slices (32 splits, 768 blocks, bf16 in) ------
__global__ __launch_bounds__(256) void calc_M(
    const u16* __restrict__ timekb, const u16* __restrict__ kvb,
    float* __restrict__ Mpart) {
  int blk = blockIdx.x;  // bh*32 + split
  int split = blk & 31;
  int bh = blk >> 5;
  int b = bh / HH, h = bh % HH;
  __shared__ float Tk[64][68];
  __shared__ float Kv[64][68];
  int tid = threadIdx.x;
  int tx = tid & 15, ty = tid >> 4;
  float acc[4][4] = {};
  int t0 = split * 64;
#pragma unroll
  for (int p = 0; p < 4; ++p) {
    int f = tid + 256 * p;
    int r = f >> 4, c4 = (f & 15) << 2;
    int t = t0 + r;
    us4 tk = *(const us4*)&timekb[(size_t)t * DD + h * DHH + c4];
    us4 kv = *(const us4*)&kvb[((size_t)(b * TT + t) * HH + h) * 64 + c4];
#pragma unroll
    for (int j = 0; j < 4; ++j) {
      Tk[r][c4 + j] = bf2f(tk[j]);
      Kv[r][c4 + j] = bf2f(kv[j]);
    }
  }
  __syncthreads();
#pragma unroll
  for (int kk = 0; kk < 64; ++kk) {
    v4 a = *(const v4*)&Tk[kk][ty * 4];
    v4 bv4 = *(const v4*)&Kv[kk][tx * 4];
#pragma unroll
    for (int r = 0; r < 4; ++r)
#pragma unroll
      for (int c = 0; c < 4; ++c) acc[r][c] += a[r] * bv4[c];
  }
#pragma unroll
  for (int r = 0; r < 4; ++r)
#pragma unroll
    for (int c = 0; c < 4; ++c)
      Mpart[(size_t)blk * 4096 + (tx * 4 + c) * 64 + (ty * 4 + r)] = acc[r][c];
}

// ------- Mtb[bh][p] = sum_{s<32} Mpart[bh*32+s][p] -> bf16 (fixed order) ------
__global__ __launch_bounds__(256) void reduce_M(
    const float* __restrict__ Mpart, u16* __restrict__ Mtb) {
  int idx = blockIdx.x * 256 + threadIdx.x;
  int bh = idx >> 12;
  int p = idx & 4095;
  float s = 0.f;
#pragma unroll
  for (int sp = 0; sp < 32; ++sp)
    s += Mpart[(size_t)((bh << 5) + sp) * 4096 + p];
  Mtb[(size_t)bh * 4096 + p] = f2bf(s);
}

// ------ loading = qsum * (timeq @ M) via MFMA -> bf16 (PRE-SWIZZLED store) ----
// grid (32, 24): 64-t chunks, each wave 16 rows x 64 cols.
__global__ __launch_bounds__(256) void calc_loading_mfma(
    const u16* __restrict__ timeqb, const u16* __restrict__ Mtb,
    const float* __restrict__ qsum, u16* __restrict__ loading) {
  const int bh = blockIdx.y;
  const int b = bh / HH, h = bh % HH;
  const int t0 = blockIdx.x * 64;
  __shared__ __align__(16) u16 Ms[64 * 72];
  for (int p = threadIdx.x; p < 4096; p += 256)
    Ms[(p >> 6) * 72 + (p & 63)] = Mtb[(size_t)bh * 4096 + p];
  __syncthreads();
  const int l = threadIdx.x & 63, w = threadIdx.x >> 6;
  f4v acc[4];
#pragma unroll
  for (int n = 0; n < 4; ++n) acc[n] = (f4v){0.f, 0.f, 0.f, 0.f};
  const int arow = t0 + w * 16 + (l & 15);
  const int dcol = l & 15;
#pragma unroll
  for (int ks = 0; ks < 2; ++ks) {
    const int k0 = ks * 32 + (l >> 4) * 8;
    s8v af, bf4[4];
    af = *(const s8v*)&timeqb[(size_t)arow * DD + h * DHH + k0];
#pragma unroll
    for (int n = 0; n < 4; ++n)
      bf4[n] = *(const s8v*)&Ms[(dcol + n * 16) * 72 + k0];
#pragma unroll
    for (int n = 0; n < 4; ++n)
      acc[n] = __builtin_amdgcn_mfma_f32_16x16x32_bf16(af, bf4[n], acc[n], 0, 0, 0);
  }
  const int trow = t0 + w * 16 + (l >> 4) * 4;
  float qs[4];
#pragma unroll
  for (int r = 0; r < 4; ++r)
    qs[r] = qsum[(b * TT + trow + r) * HH + h];
#pragma unroll
  for (int n = 0; n < 4; ++n)
#pragma unroll
    for (int r = 0; r < 4; ++r) {
      int i = b * TT + trow + r;
      int col = h * DHH + n * 16 + (l & 15);
      loading[(size_t)i * DD + swz_col(i, col)] = f2bf(qs[r] * acc[n][r]);
    }
}

// ------ gemm_out: 64x64 tiles, 768 blocks (3/CU); 3-buf single-barrier ------
__global__ __launch_bounds__(256) void gemm_out(
    const u16* __restrict__ A, const u16* __restrict__ B, float* __restrict__ C,
    const float* __restrict__ bias, const float* __restrict__ res) {
  __shared__ __align__(16) u16 As[3][2048];
  __shared__ __align__(16) u16 Bs[3][2048];
  const int tid = threadIdx.x;
  const int l = tid & 63;
  const int w = tid >> 6;
  const int wr = w >> 1, wc = w & 1;
  const int i0 = blockIdx.y * 64, j0 = blockIdx.x * 64;
  const int srow = tid >> 2, scol = (tid & 3) * 8;
  const u16* gA0 = A + (size_t)(i0 + srow) * 768 + scol;
  const u16* gB0 = B + (size_t)(j0 + srow) * 768 + scol;
  const int lo = tid * 8;
  f4v acc[2][2];
#pragma unroll
  for (int m = 0; m < 2; ++m)
#pragma unroll
    for (int n = 0; n < 2; ++n) acc[m][n] = (f4v){0.f, 0.f, 0.f, 0.f};

#define STAGE2(kt, b)                 \
  do {                                \
    int kb_ = (kt) << 5;              \
    gload16(gA0 + kb_, &As[b][lo]);   \
    gload16(gB0 + kb_, &Bs[b][lo]);   \
  } while (0)

  STAGE2(0, 0);
  STAGE2(1, 1);
  int aoff[2], boff[2];
#pragma unroll
  for (int m = 0; m < 2; ++m) {
    int row = wr * 32 + (l & 15) + m * 16;
    aoff[m] = row * 32 + (((l >> 4) ^ ((row >> 1) & 3)) << 3);
  }
#pragma unroll
  for (int n = 0; n < 2; ++n) {
    int row = wc * 32 + (l & 15) + n * 16;
    boff[n] = row * 32 + (((l >> 4) ^ ((row >> 1) & 3)) << 3);
  }
  int cb = 0;
  for (int kt = 0; kt < 24; ++kt) {
    if (kt < 23) wait_vm2();
    else wait_vm0();
    raw_barrier();
    if (kt + 2 < 24) STAGE2(kt + 2, (cb + 2) % 3);
    s8v af[2], bf4[2];
#pragma unroll
    for (int m = 0; m < 2; ++m) af[m] = *(const s8v*)&As[cb][aoff[m]];
#pragma unroll
    for (int n = 0; n < 2; ++n) bf4[n] = *(const s8v*)&Bs[cb][boff[n]];
#pragma unroll
    for (int m = 0; m < 2; ++m)
#pragma unroll
      for (int n = 0; n < 2; ++n)
        acc[m][n] =
            __builtin_amdgcn_mfma_f32_16x16x32_bf16(af[m], bf4[n], acc[m][n], 0, 0, 0);
    cb = (cb == 2) ? 0 : cb + 1;
  }
  const int crow = i0 + wr * 32 + (l >> 4) * 4;
  const int ccol = j0 + wc * 32 + (l & 15);
#pragma unroll
  for (int m = 0; m < 2; ++m)
#pragma unroll
    for (int n = 0; n < 2; ++n) {
      int col = ccol + n * 16;
      size_t base = (size_t)(crow + m * 16) * 768 + col;
#pragma unroll
      for (int r = 0; r < 4; ++r)
        C[base + (size_t)r * 768] =
            acc[m][n][r] + bias[col] + res[base + (size_t)r * 768];
    }
}

// ---------------- LayerNorm ----------------
__global__ __launch_bounds__(256) void layernorm(
    const float* __restrict__ X, const float* __restrict__ gamma,
    const float* __restrict__ beta, float* __restrict__ out) {
  int i = blockIdx.x;
  const float* x = X + (size_t)i * 768;
  float vals[3];
  float s = 0.f, s2 = 0.f;
#pragma unroll
  for (int p = 0; p < 3; ++p) {
    float v = x[threadIdx.x + 256 * p];
    vals[p] = v;
    s += v;
    s2 += v * v;
  }
  s = wave_sum(s);
  s2 = wave_sum(s2);
  __shared__ float red[8];
  int w = threadIdx.x >> 6;
  if ((threadIdx.x & 63) == 0) {
    red[w] = s;
    red[4 + w] = s2;
  }
  __syncthreads();
  float stot = red[0] + red[1] + red[2] + red[3];
  float s2tot = red[4] + red[5] + red[6] + red[7];
  float mu = stot * (1.f / 768.f);
  float var = s2tot * (1.f / 768.f) - mu * mu;
  float rs = rsqrtf(var + 1e-5f);
#pragma unroll
  for (int p = 0; p < 3; ++p) {
    int j = threadIdx.x + 256 * p;
    out[(size_t)i * 768 + j] = (vals[p] - mu) * rs * gamma[j] + beta[j];
  }
}

extern "C" void kernel_launch(void* const* d_in, const int* in_sizes, int n_in,
                              void* d_out, int out_size, void* d_ws,
                              size_t ws_size, hipStream_t stream) {
  const float* states = (const float*)d_in[0];
  const int* amask    = (const int*)d_in[1];
  const float* Wq     = (const float*)d_in[2];
  const float* Wk     = (const float*)d_in[3];
  const float* bk     = (const float*)d_in[4];
  const float* Wv     = (const float*)d_in[5];
  const float* bv     = (const float*)d_in[6];
  const float* Wo     = (const float*)d_in[7];
  const float* bo     = (const float*)d_in[8];
  const float* qb     = (const float*)d_in[9];
  const float* tang   = (const float*)d_in[10];
  const float* hdelta = (const float*)d_in[11];
  const float* gamma  = (const float*)d_in[12];
  const float* beta   = (const float*)d_in[13];
  float* out = (float*)d_out;
  float* ws = (float*)d_ws;

  // Non-overlapping workspace layout (float-unit offsets; 55.4 MB total).
  u16* timeqb = (u16*)(ws + 0);          // 1,572,864 u16 = [0, 786432)
  u16* timekb = (u16*)(ws + 786432);     // 1,572,864 u16 = [786432, 1572864)
  u16* Abf    = (u16*)(ws + 1572864);    // 3,145,728 u16 = [1572864, 3145728)
  u16* Wqb    = (u16*)(ws + 3145728);    //   589,824 u16 = [3145728, 3440640)
  u16* Wkvb   = (u16*)(ws + 3440640);    // 1,179,648 u16 = [3440640, 4030464)
  u16* Wob    = (u16*)(ws + 4030464);    //   589,824 u16 = [4030464, 4325376)
  float* qsum = ws + 4325376;            //    49,152 f   = [4325376, 4374528)
  u16* kvb    = (u16*)(ws + 4374528);    // 3,145,728 u16 = [4374528, 5947392)
  float* Mpart= ws + 5947392;            // 3,145,728 f   = [5947392, 9093120)
  u16* Mtb    = (u16*)(ws + 9093120);    //    98,304 u16 = [9093120, 9142272)
  u16* loadb  = (u16*)(ws + 9142272);    // 3,145,728 u16 = [9142272, 10715136)
  float* xbuf = ws + 10715136;           // 3,145,728 f   = [10715136, 13860864)

  prep<<<5568, 256, 0, stream>>>(tang, hdelta, states, Wq, Wk, Wv, Wo, timeqb,
                                 timekb, Abf, Wqb, Wkvb, Wob);
  gemm_qkv_fused<<<1152, 256, 0, stream>>>(Abf, Wqb, Wkvb, qb, bk, bv,
                                           amask, qsum, kvb);
  calc_M<<<768, 256, 0, stream>>>(timekb, kvb, Mpart);
  reduce_M<<<384, 256, 0, stream>>>(Mpart, Mtb);
  calc_loading_mfma<<<dim3(32, 24), 256, 0, stream>>>(timeqb, Mtb, qsum, loadb);
  gemm_out<<<dim3(12, 64), 256, 0, stream>>>(loadb, Wob, xbuf, bo, states);
  layernorm<<<4096, 256, 0, stream>>>(xbuf, gamma, beta, out);
}